// Round 5
// baseline (1462.781 us; speedup 1.0000x reference)
//
#include <hip/hip_runtime.h>
#include <hip/hip_bf16.h>
#include <math.h>

// ---- problem dims ----
constexpr int BATCH = 2;
constexpr int SEQ   = 4096;
constexpr int DM    = 1024;   // DIM_MODEL
constexpr int DSTATE= 128;
constexpr int DH    = 64;     // head dim
constexpr int NH    = 32;     // heads
constexpr int CHK   = 256;    // chunk
constexpr int DI    = 2048;   // DIM_INNER = DIM_SSD
constexpr int DPROJ = 4384;   // 2*DI + 2*DSTATE + NH
constexpr int CONVD = 2304;   // DI + 2*DSTATE
constexpr int NC    = SEQ / CHK;     // 16
constexpr int BL    = BATCH * SEQ;   // 8192

// ---- workspace layout (bytes); total ~244 MiB ----
// yb (BL*DI*4) aliases xpre (BL*CONVD*4): xpre dead after conv.
// states/prevs live in d_out (exactly BL*DM*4), overwritten by out_proj GEMM.
constexpr long SZ_Z    = (long)BL*DI*4;
constexpr long SZ_XPRE = (long)BL*CONVD*4;
constexpr long SZ_DTRW = (long)BL*NH*4;
constexpr long SZ_XBC  = (long)BL*CONVD*4;
constexpr long SZ_DT   = (long)BL*NH*4;
constexpr long SZ_ACS  = (long)BL*NH*4;
constexpr long SZ_CB   = (long)BATCH*NC*CHK*CHK*4;
constexpr long SZ_WIS  = (long)DPROJ*2*DM*2;
constexpr long SZ_WOS  = (long)DM*2*DI*2;

constexpr long OFF_Z    = 0;
constexpr long OFF_XPRE = OFF_Z    + SZ_Z;
constexpr long OFF_DTRW = OFF_XPRE + SZ_XPRE;
constexpr long OFF_XBC  = OFF_DTRW + SZ_DTRW;
constexpr long OFF_DT   = OFF_XBC  + SZ_XBC;
constexpr long OFF_ACS  = OFF_DT   + SZ_DT;
constexpr long OFF_CB   = OFF_ACS  + SZ_ACS;
constexpr long OFF_WIS  = OFF_CB   + SZ_CB;
constexpr long OFF_WOS  = OFF_WIS  + SZ_WIS;

using bf16x8 = __attribute__((ext_vector_type(8))) short;
using us8    = __attribute__((ext_vector_type(8))) unsigned short;
using f32x4  = __attribute__((ext_vector_type(4))) float;

__device__ __forceinline__ unsigned short f2bf(float x) {
    __hip_bfloat16 h = __float2bfloat16(x);   // HW cvt (RNE)
    return *reinterpret_cast<unsigned short*>(&h);
}
__device__ __forceinline__ float bf2f(unsigned short s) {
    return __uint_as_float((unsigned)s << 16);
}

// convert 8 f32 -> hi/lo bf16 vectors (compiler fuses into v_cvt_pk_bf16_f32)
__device__ __forceinline__ void cvt8(const float4 a, const float4 b, us8& h, us8& l) {
    float vv[8] = {a.x, a.y, a.z, a.w, b.x, b.y, b.z, b.w};
    us8 hh, ll;
#pragma unroll
    for (int j = 0; j < 8; ++j) {
        hh[j] = f2bf(vv[j]);
        ll[j] = f2bf(vv[j] - bf2f(hh[j]));
    }
    h = hh; l = ll;
}

// ======================================================================
// split2 (weights only): src f32 [rows][K] -> dst bf16 [rows][2K]=[hi|lo]
// ======================================================================
__global__ void mamba_split2(const float* __restrict__ src, unsigned short* __restrict__ dst,
                             long rows, int K)
{
    long idx = (long)blockIdx.x * blockDim.x + threadIdx.x;
    long total = rows * (K / 4);
    if (idx >= total) return;
    long r  = idx / (K / 4);
    int  kq = (int)(idx % (K / 4)) * 4;

    float4 v = *reinterpret_cast<const float4*>(&src[r * (long)K + kq]);
    float vv[4] = {v.x, v.y, v.z, v.w};
    unsigned short hi[4], lo[4];
#pragma unroll
    for (int j = 0; j < 4; ++j) {
        hi[j] = f2bf(vv[j]);
        lo[j] = f2bf(vv[j] - bf2f(hi[j]));
    }
    unsigned short* dd = dst + r * (long)(2 * K);
    *reinterpret_cast<ushort4*>(&dd[kq])     = make_ushort4(hi[0], hi[1], hi[2], hi[3]);
    *reinterpret_cast<ushort4*>(&dd[K + kq]) = make_ushort4(lo[0], lo[1], lo[2], lo[3]);
}

// ======================================================================
// split-bf16 MFMA GEMM (NT): C[m][n] = sum_k A[m][k]*B[n][k], fp32-accurate
// A: f32 [M][lda], converted hi/lo on the fly during staging.
// Bs: bf16 [Nrows][2*Kr] = [hi|lo] (pre-split weights).
// Per 32-wide K-tile: acc += Ahi*Bhi + Alo*Bhi + Ahi*Blo  (3 MFMA/frag pair)
// M%128==0; grid.x covers ceil(N/128) with Nrows guard; Kr%32==0.
// 256 thr = 4 waves (2x2), each wave 64x64 via 4x4 frags of 16x16x32.
// ======================================================================
__launch_bounds__(256, 2)
__global__ void gemm_asplit(const float* __restrict__ A, int lda,
                            const unsigned short* __restrict__ Bs, int Nrows,
                            float* __restrict__ C, int ldc, int Kr)
{
    constexpr int LK = 40;   // 32 + 8 pad shorts; 80B rows, 16B-aligned slots
    __shared__ unsigned short sAhi[128 * LK];
    __shared__ unsigned short sAlo[128 * LK];
    __shared__ unsigned short sBhi[128 * LK];
    __shared__ unsigned short sBlo[128 * LK];

    const int tid  = threadIdx.x;
    const int lane = tid & 63;
    const int wave = tid >> 6;
    const int wr = wave >> 1, wc = wave & 1;
    const long m0 = (long)blockIdx.y * 128;
    const long n0 = (long)blockIdx.x * 128;
    const int ldb = 2 * Kr;

    // staging ownership: row = tid>>1 (0..127), col0 = (tid&1)*16 (of 32 k)
    const int row  = tid >> 1;
    const int col0 = (tid & 1) * 16;
    const float* Ap = A + (m0 + row) * (long)lda + col0;
    const long brow = n0 + row;
    const bool bok  = brow < Nrows;
    const unsigned short* Bph = Bs + brow * (long)ldb + col0;        // hi seg
    const unsigned short* Bpl = Bs + brow * (long)ldb + Kr + col0;   // lo seg
    unsigned short* wAh = &sAhi[row * LK + col0];
    unsigned short* wAl = &sAlo[row * LK + col0];
    unsigned short* wBh = &sBhi[row * LK + col0];
    unsigned short* wBl = &sBlo[row * LK + col0];

    const int fr  = lane & 15;
    const int fkb = (lane >> 4) * 8;

    f32x4 acc[4][4];
#pragma unroll
    for (int i = 0; i < 4; ++i)
#pragma unroll
        for (int j = 0; j < 4; ++j) acc[i][j] = (f32x4){0.f, 0.f, 0.f, 0.f};

    const int4 zero4 = make_int4(0, 0, 0, 0);
    float4 fa0 = *reinterpret_cast<const float4*>(Ap + 0);
    float4 fa1 = *reinterpret_cast<const float4*>(Ap + 4);
    float4 fa2 = *reinterpret_cast<const float4*>(Ap + 8);
    float4 fa3 = *reinterpret_cast<const float4*>(Ap + 12);
    int4 rbh0 = bok ? *reinterpret_cast<const int4*>(Bph + 0) : zero4;
    int4 rbh1 = bok ? *reinterpret_cast<const int4*>(Bph + 8) : zero4;
    int4 rbl0 = bok ? *reinterpret_cast<const int4*>(Bpl + 0) : zero4;
    int4 rbl1 = bok ? *reinterpret_cast<const int4*>(Bpl + 8) : zero4;
    us8 cah0, cah1, cal0, cal1;
    cvt8(fa0, fa1, cah0, cal0);
    cvt8(fa2, fa3, cah1, cal1);

    for (int kt = 0; kt < Kr; kt += 32) {
        *reinterpret_cast<us8*>(wAh)     = cah0;
        *reinterpret_cast<us8*>(wAh + 8) = cah1;
        *reinterpret_cast<us8*>(wAl)     = cal0;
        *reinterpret_cast<us8*>(wAl + 8) = cal1;
        *reinterpret_cast<int4*>(wBh)     = rbh0;
        *reinterpret_cast<int4*>(wBh + 8) = rbh1;
        *reinterpret_cast<int4*>(wBl)     = rbl0;
        *reinterpret_cast<int4*>(wBl + 8) = rbl1;
        __syncthreads();

        const int kn = kt + 32;
        if (kn < Kr) {   // prefetch next K-tile (overlaps MFMA below)
            fa0 = *reinterpret_cast<const float4*>(Ap + kn + 0);
            fa1 = *reinterpret_cast<const float4*>(Ap + kn + 4);
            fa2 = *reinterpret_cast<const float4*>(Ap + kn + 8);
            fa3 = *reinterpret_cast<const float4*>(Ap + kn + 12);
            rbh0 = bok ? *reinterpret_cast<const int4*>(Bph + kn + 0) : zero4;
            rbh1 = bok ? *reinterpret_cast<const int4*>(Bph + kn + 8) : zero4;
            rbl0 = bok ? *reinterpret_cast<const int4*>(Bpl + kn + 0) : zero4;
            rbl1 = bok ? *reinterpret_cast<const int4*>(Bpl + kn + 8) : zero4;
        }

        bf16x8 ah[4], al[4], bh[4], bl[4];
#pragma unroll
        for (int mi = 0; mi < 4; ++mi) {
            ah[mi] = *reinterpret_cast<const bf16x8*>(&sAhi[(wr * 64 + mi * 16 + fr) * LK + fkb]);
            al[mi] = *reinterpret_cast<const bf16x8*>(&sAlo[(wr * 64 + mi * 16 + fr) * LK + fkb]);
        }
#pragma unroll
        for (int ni = 0; ni < 4; ++ni) {
            bh[ni] = *reinterpret_cast<const bf16x8*>(&sBhi[(wc * 64 + ni * 16 + fr) * LK + fkb]);
            bl[ni] = *reinterpret_cast<const bf16x8*>(&sBlo[(wc * 64 + ni * 16 + fr) * LK + fkb]);
        }
#pragma unroll
        for (int mi = 0; mi < 4; ++mi)
#pragma unroll
            for (int ni = 0; ni < 4; ++ni) {
                acc[mi][ni] = __builtin_amdgcn_mfma_f32_16x16x32_bf16(ah[mi], bh[ni], acc[mi][ni], 0, 0, 0);
                acc[mi][ni] = __builtin_amdgcn_mfma_f32_16x16x32_bf16(al[mi], bh[ni], acc[mi][ni], 0, 0, 0);
                acc[mi][ni] = __builtin_amdgcn_mfma_f32_16x16x32_bf16(ah[mi], bl[ni], acc[mi][ni], 0, 0, 0);
            }

        if (kn < Kr) {   // convert prefetched A (VALU overlaps MFMA drain)
            cvt8(fa0, fa1, cah0, cal0);
            cvt8(fa2, fa3, cah1, cal1);
        }
        __syncthreads();
    }

    // epilogue: C/D layout col=lane&15, row=(lane>>4)*4+j  [m89-verified]
    const int crow = (lane >> 4) * 4;
#pragma unroll
    for (int mi = 0; mi < 4; ++mi) {
        long gm = m0 + wr * 64 + mi * 16 + crow;
#pragma unroll
        for (int ni = 0; ni < 4; ++ni) {
            long gn = n0 + wc * 64 + ni * 16 + fr;
            if (gn < Nrows) {
#pragma unroll
                for (int j = 0; j < 4; ++j)
                    C[(gm + j) * (long)ldc + gn] = acc[mi][ni][j];
            }
        }
    }
}

// ======================================================================
// fp32 GEMM (NT) — small CB batched GEMM only
// ======================================================================
template<int BM,int BN,int BK,int TM,int TN>
__launch_bounds__(256)
__global__ void mamba_gemm_nt(const float* __restrict__ A, const float* __restrict__ Bw,
                              float* __restrict__ C,
                              int M, int N, int K, int lda, int ldb, int ldc,
                              long strideA, long strideB, long strideC)
{
    constexpr int NT = 256;
    const int batch = blockIdx.z;
    A  += (long)batch * strideA;
    Bw += (long)batch * strideB;
    C  += (long)batch * strideC;
    const int m0 = blockIdx.y * BM;
    const int n0 = blockIdx.x * BN;

    __shared__ float sA[BK][BM+4];
    __shared__ float sB[BK][BN+4];

    const int tid = threadIdx.x;
    const int tx  = tid % (BN/TN);
    const int ty  = tid / (BN/TN);

    float acc[TM][TN];
#pragma unroll
    for (int i = 0; i < TM; ++i)
#pragma unroll
        for (int j = 0; j < TN; ++j) acc[i][j] = 0.f;

    constexpr int AV = (BM*BK)/(NT*4);
    constexpr int BV = (BN*BK)/(NT*4);
    static_assert(AV >= 1 && BV >= 1, "tile too small");

    for (int k0 = 0; k0 < K; k0 += BK) {
#pragma unroll
        for (int v = 0; v < AV; ++v) {
            int idx = tid + v*NT;
            int m   = idx / (BK/4);
            int kq  = idx % (BK/4);
            int gm  = m0 + m;
            float4 val = make_float4(0.f,0.f,0.f,0.f);
            if (gm < M) val = *reinterpret_cast<const float4*>(&A[(long)gm*lda + k0 + kq*4]);
            sA[kq*4+0][m] = val.x; sA[kq*4+1][m] = val.y;
            sA[kq*4+2][m] = val.z; sA[kq*4+3][m] = val.w;
        }
#pragma unroll
        for (int v = 0; v < BV; ++v) {
            int idx = tid + v*NT;
            int n   = idx / (BK/4);
            int kq  = idx % (BK/4);
            int gn  = n0 + n;
            float4 val = make_float4(0.f,0.f,0.f,0.f);
            if (gn < N) val = *reinterpret_cast<const float4*>(&Bw[(long)gn*ldb + k0 + kq*4]);
            sB[kq*4+0][n] = val.x; sB[kq*4+1][n] = val.y;
            sB[kq*4+2][n] = val.z; sB[kq*4+3][n] = val.w;
        }
        __syncthreads();
#pragma unroll
        for (int k = 0; k < BK; ++k) {
            float ar[TM], br[TN];
#pragma unroll
            for (int i = 0; i < TM; ++i) ar[i] = sA[k][ty*TM+i];
#pragma unroll
            for (int j = 0; j < TN; ++j) br[j] = sB[k][tx*TN+j];
#pragma unroll
            for (int i = 0; i < TM; ++i)
#pragma unroll
                for (int j = 0; j < TN; ++j) acc[i][j] += ar[i]*br[j];
        }
        __syncthreads();
    }

#pragma unroll
    for (int i = 0; i < TM; ++i) {
        int gm = m0 + ty*TM + i;
        if (gm >= M) continue;
#pragma unroll
        for (int j = 0; j < TN; ++j) {
            int gn = n0 + tx*TN + j;
            if (gn < N) C[(long)gm*ldc + gn] = acc[i][j];
        }
    }
}

// ======================================================================
// Depthwise causal conv (width 4) + SiLU: xpre[BL][CONVD] -> xBC[BL][CONVD]
// ======================================================================
__global__ void mamba_conv_silu(const float* __restrict__ xpre,
                                const float* __restrict__ conv_w,
                                const float* __restrict__ conv_b,
                                float* __restrict__ xBC)
{
    long idx = (long)blockIdx.x * blockDim.x + threadIdx.x;
    if (idx >= (long)BL*(CONVD/4)) return;
    int ch4 = (int)(idx % (CONVD/4)) * 4;
    long bl = idx / (CONVD/4);
    int l = (int)(bl % SEQ);
    long brow = bl - l;

    float4 w0 = *reinterpret_cast<const float4*>(&conv_w[(ch4+0)*4]);
    float4 w1 = *reinterpret_cast<const float4*>(&conv_w[(ch4+1)*4]);
    float4 w2 = *reinterpret_cast<const float4*>(&conv_w[(ch4+2)*4]);
    float4 w3 = *reinterpret_cast<const float4*>(&conv_w[(ch4+3)*4]);
    float4 accv = *reinterpret_cast<const float4*>(&conv_b[ch4]);
    float acc[4] = {accv.x, accv.y, accv.z, accv.w};
    const float wk[4][4] = {{w0.x,w0.y,w0.z,w0.w},{w1.x,w1.y,w1.z,w1.w},
                            {w2.x,w2.y,w2.z,w2.w},{w3.x,w3.y,w3.z,w3.w}};
#pragma unroll
    for (int k = 0; k < 4; ++k) {
        int lk = l - 3 + k;
        if (lk >= 0) {
            float4 v = *reinterpret_cast<const float4*>(&xpre[(brow + lk)*CONVD + ch4]);
            acc[0] += wk[0][k]*v.x; acc[1] += wk[1][k]*v.y;
            acc[2] += wk[2][k]*v.z; acc[3] += wk[3][k]*v.w;
        }
    }
    float4 o;
    o.x = acc[0] / (1.f + expf(-acc[0]));
    o.y = acc[1] / (1.f + expf(-acc[1]));
    o.z = acc[2] / (1.f + expf(-acc[2]));
    o.w = acc[3] / (1.f + expf(-acc[3]));
    *reinterpret_cast<float4*>(&xBC[bl*CONVD + ch4]) = o;
}

// ======================================================================
// dt = softplus(dt_raw + bias); a = dt*A; inclusive cumsum per (b,c,h)
// ======================================================================
__global__ void mamba_dt_cumsum(const float* __restrict__ dtraw,
                                const float* __restrict__ dt_bias,
                                const float* __restrict__ A_log,
                                float* __restrict__ dt_o,
                                float* __restrict__ acs_o)
{
    int blk = blockIdx.x;           // bc*NH + h
    int h  = blk % NH;
    int bc = blk / NH;
    int j  = threadIdx.x;
    long bl = (long)bc*CHK + j;

    float raw = dtraw[bl*NH + h] + dt_bias[h];
    float dt  = (raw > 20.f) ? raw : log1pf(expf(raw));
    float A   = -expf(A_log[h]);
    float a   = dt * A;

    __shared__ float s[CHK];
    s[j] = a;
    __syncthreads();
    for (int off = 1; off < CHK; off <<= 1) {
        float v = (j >= off) ? s[j-off] : 0.f;
        __syncthreads();
        s[j] += v;
        __syncthreads();
    }
    dt_o [bl*NH + h] = dt;
    acs_o[bl*NH + h] = s[j];
}

// ======================================================================
// states[bc][h][p][n] = sum_j dt[j]*exp(acs_last-acs[j]) * x[j][p] * B[j][n]
// (states buffer = d_out, overwritten later by out_proj GEMM)
// ======================================================================
__launch_bounds__(256)
__global__ void mamba_states(const float* __restrict__ xBC,
                             const float* __restrict__ dt,
                             const float* __restrict__ acs,
                             float* __restrict__ states)
{
    int blk = blockIdx.x;
    int h  = blk % NH;
    int bc = blk / NH;
    const int tid = threadIdx.x;
    const int tn = tid % 16;
    const int tp = tid / 16;

    __shared__ float sx[16][DH+1];
    __shared__ float sb[16][DSTATE+1];

    float acc[4][8];
#pragma unroll
    for (int i=0;i<4;++i)
#pragma unroll
        for (int j=0;j<8;++j) acc[i][j]=0.f;

    float acs_last = acs[((long)bc*CHK + CHK-1)*NH + h];

    for (int j0 = 0; j0 < CHK; j0 += 16) {
        {
            int r  = tid / 16;
            int cq = tid % 16;
            long bl = (long)bc*CHK + j0 + r;
            float4 v = *reinterpret_cast<const float4*>(&xBC[bl*CONVD + h*DH + cq*4]);
            float w = dt[bl*NH+h] * expf(acs_last - acs[bl*NH+h]);
            sx[r][cq*4+0]=v.x*w; sx[r][cq*4+1]=v.y*w;
            sx[r][cq*4+2]=v.z*w; sx[r][cq*4+3]=v.w*w;
        }
        {
#pragma unroll
            for (int t = 0; t < 2; ++t) {
                int idx = tid + t*256;
                int r  = idx / 32;
                int cq = idx % 32;
                long bl = (long)bc*CHK + j0 + r;
                float4 v = *reinterpret_cast<const float4*>(&xBC[bl*CONVD + DI + cq*4]);
                sb[r][cq*4+0]=v.x; sb[r][cq*4+1]=v.y;
                sb[r][cq*4+2]=v.z; sb[r][cq*4+3]=v.w;
            }
        }
        __syncthreads();
#pragma unroll
        for (int jj = 0; jj < 16; ++jj) {
            float xr[4], br[8];
#pragma unroll
            for (int i=0;i<4;++i) xr[i]=sx[jj][tp*4+i];
#pragma unroll
            for (int j=0;j<8;++j) br[j]=sb[jj][tn*8+j];
#pragma unroll
            for (int i=0;i<4;++i)
#pragma unroll
                for (int j=0;j<8;++j) acc[i][j] += xr[i]*br[j];
        }
        __syncthreads();
    }

    float* out = states + (long)blk * DH * DSTATE;
#pragma unroll
    for (int i=0;i<4;++i)
#pragma unroll
        for (int j=0;j<8;++j)
            out[(tp*4+i)*DSTATE + tn*8+j] = acc[i][j];
}

// ======================================================================
// inter-chunk scan, IN-PLACE: st[c] := carry before chunk c
// ======================================================================
__global__ void mamba_scan(float* __restrict__ st,
                           const float* __restrict__ acs)
{
    long idx = (long)blockIdx.x * blockDim.x + threadIdx.x;
    if (idx >= (long)BATCH*NH*DH*DSTATE) return;
    int n = (int)(idx % DSTATE);
    int p = (int)((idx / DSTATE) % DH);
    int h = (int)((idx / ((long)DSTATE*DH)) % NH);
    int b = (int)( idx / ((long)DSTATE*DH*NH));

    float carry = 0.f;
    for (int c = 0; c < NC; ++c) {
        int bc = b*NC + c;
        long o = ((long)(bc*NH + h)*DH + p)*DSTATE + n;
        float s = st[o];
        st[o] = carry;
        float dchunk = expf(acs[((long)bc*CHK + CHK-1)*NH + h]);
        carry = carry*dchunk + s;
    }
}

// ======================================================================
// y = intra-chunk + inter-chunk + D skip
// ======================================================================
__launch_bounds__(256)
__global__ void mamba_y(const float* __restrict__ xBC,
                        const float* __restrict__ CB,
                        const float* __restrict__ dt,
                        const float* __restrict__ acs,
                        const float* __restrict__ prevs,
                        const float* __restrict__ Dp,
                        float* __restrict__ y)
{
    const int blk = blockIdx.y;
    const int h  = blk % NH;
    const int bc = blk / NH;
    const int i0 = blockIdx.x * 64;
    const int tid = threadIdx.x;
    const int tp = tid % 16;
    const int ti = tid / 16;

    __shared__ float sU[16][64+1];
    __shared__ float sV[16][64+1];
    __shared__ float sAj[16];

    float ai[4];
#pragma unroll
    for (int q=0;q<4;++q)
        ai[q] = acs[((long)bc*CHK + i0 + ti*4 + q)*NH + h];

    float acc[4][4]; float acc2[4][4];
#pragma unroll
    for (int q=0;q<4;++q)
#pragma unroll
        for (int r=0;r<4;++r) { acc[q][r]=0.f; acc2[q][r]=0.f; }

    for (int j0 = 0; j0 <= i0 + 63; j0 += 16) {
#pragma unroll
        for (int t = 0; t < 4; ++t) {
            int e  = tid + t*256;
            int ii = e / 16, jj = e % 16;
            sU[jj][ii] = CB[(long)bc*CHK*CHK + (long)(i0+ii)*CHK + (j0+jj)];
        }
        {
            int r  = tid / 16;
            int cq = tid % 16;
            long bl = (long)bc*CHK + j0 + r;
            float4 v = *reinterpret_cast<const float4*>(&xBC[bl*CONVD + h*DH + cq*4]);
            float w = dt[bl*NH+h];
            sV[r][cq*4+0]=v.x*w; sV[r][cq*4+1]=v.y*w;
            sV[r][cq*4+2]=v.z*w; sV[r][cq*4+3]=v.w*w;
        }
        if (tid < 16) sAj[tid] = acs[((long)bc*CHK + j0 + tid)*NH + h];
        __syncthreads();
#pragma unroll
        for (int jj = 0; jj < 16; ++jj) {
            int j = j0 + jj;
            float aj = sAj[jj];
            float xr[4];
#pragma unroll
            for (int r=0;r<4;++r) xr[r]=sV[jj][tp*4+r];
#pragma unroll
            for (int q=0;q<4;++q) {
                int i = i0 + ti*4 + q;
                if (j <= i) {
                    float f = expf(ai[q]-aj) * sU[jj][ti*4+q];
#pragma unroll
                    for (int r=0;r<4;++r) acc[q][r] += f*xr[r];
                }
            }
        }
        __syncthreads();
    }

    for (int n0 = 0; n0 < DSTATE; n0 += 16) {
#pragma unroll
        for (int t = 0; t < 4; ++t) {
            int e  = tid + t*256;
            int ii = e / 16, nn = e % 16;
            sU[nn][ii] = xBC[(long)(bc*CHK + i0 + ii)*CONVD + DI + DSTATE + n0 + nn];
            sV[nn][ii] = prevs[((long)blk*DH + ii)*DSTATE + n0 + nn];
        }
        __syncthreads();
#pragma unroll
        for (int nn = 0; nn < 16; ++nn) {
            float cr[4], pr[4];
#pragma unroll
            for (int q=0;q<4;++q) cr[q]=sU[nn][ti*4+q];
#pragma unroll
            for (int r=0;r<4;++r) pr[r]=sV[nn][tp*4+r];
#pragma unroll
            for (int q=0;q<4;++q)
#pragma unroll
                for (int r=0;r<4;++r) acc2[q][r] += cr[q]*pr[r];
        }
        __syncthreads();
    }

    float Dh = Dp[h];
#pragma unroll
    for (int q=0;q<4;++q) {
        long bl = (long)bc*CHK + i0 + ti*4 + q;
        float e = expf(ai[q]);
        float4 xv = *reinterpret_cast<const float4*>(&xBC[bl*CONVD + h*DH + tp*4]);
        float4 o;
        o.x = acc[q][0] + e*acc2[q][0] + xv.x*Dh;
        o.y = acc[q][1] + e*acc2[q][1] + xv.y*Dh;
        o.z = acc[q][2] + e*acc2[q][2] + xv.z*Dh;
        o.w = acc[q][3] + e*acc2[q][3] + xv.w*Dh;
        *reinterpret_cast<float4*>(&y[bl*DI + h*DH + tp*4]) = o;
    }
}

// ======================================================================
// gate + RMSNorm, IN-PLACE on y (fp32); out_proj GEMM splits on the fly
// ======================================================================
__launch_bounds__(256)
__global__ void mamba_gate_norm(const float* __restrict__ zbuf,
                                const float* __restrict__ norm_w,
                                float* __restrict__ y)
{
    long bl = blockIdx.x;
    const float* zrow = zbuf + bl*DI;
    float* yrow = y + bl*DI;
    const int base = threadIdx.x * 8;

    float vals[8];
    float ss = 0.f;
#pragma unroll
    for (int half = 0; half < 2; ++half) {
        float4 zv = *reinterpret_cast<const float4*>(&zrow[base + half*4]);
        float4 yv = *reinterpret_cast<const float4*>(&yrow[base + half*4]);
        float zz[4] = {zv.x, zv.y, zv.z, zv.w};
        float yy[4] = {yv.x, yv.y, yv.z, yv.w};
#pragma unroll
        for (int t = 0; t < 4; ++t) {
            float v = yy[t] * (zz[t] / (1.f + expf(-zz[t])));
            vals[half*4+t] = v;
            ss += v*v;
        }
    }
#pragma unroll
    for (int o = 1; o < 64; o <<= 1) ss += __shfl_xor(ss, o, 64);

    __shared__ float red[4];
    int wid = threadIdx.x >> 6;
    if ((threadIdx.x & 63) == 0) red[wid] = ss;
    __syncthreads();
    ss = red[0] + red[1] + red[2] + red[3];
    float scale = rsqrtf(ss / DI + 1e-5f);

#pragma unroll
    for (int half = 0; half < 2; ++half) {
        float4 nw = *reinterpret_cast<const float4*>(&norm_w[base + half*4]);
        float4 o;
        o.x = vals[half*4+0] * scale * nw.x;
        o.y = vals[half*4+1] * scale * nw.y;
        o.z = vals[half*4+2] * scale * nw.z;
        o.w = vals[half*4+3] * scale * nw.w;
        *reinterpret_cast<float4*>(&yrow[base + half*4]) = o;
    }
}

// ======================================================================
extern "C" void kernel_launch(void* const* d_in, const int* in_sizes, int n_in,
                              void* d_out, int out_size, void* d_ws, size_t ws_size,
                              hipStream_t stream)
{
    const float* u         = (const float*)d_in[0];
    const float* in_proj_w = (const float*)d_in[1];
    const float* conv_w    = (const float*)d_in[2];
    const float* conv_b    = (const float*)d_in[3];
    const float* dt_bias   = (const float*)d_in[4];
    const float* A_log     = (const float*)d_in[5];
    const float* Dp        = (const float*)d_in[6];
    const float* norm_w    = (const float*)d_in[7];
    const float* out_proj_w= (const float*)d_in[8];
    float* out = (float*)d_out;

    char* ws = (char*)d_ws;
    float* zbuf  = (float*)(ws + OFF_Z);
    float* xpre  = (float*)(ws + OFF_XPRE);
    float* yb    = xpre;                       // alias: xpre dead after conv
    float* dtraw = (float*)(ws + OFF_DTRW);
    float* xBC   = (float*)(ws + OFF_XBC);
    float* dtb   = (float*)(ws + OFF_DT);
    float* acs   = (float*)(ws + OFF_ACS);
    float* CBb   = (float*)(ws + OFF_CB);
    unsigned short* wInS  = (unsigned short*)(ws + OFF_WIS);
    unsigned short* wOutS = (unsigned short*)(ws + OFF_WOS);
    float* stb = out;                          // states/prevs live in d_out

    // 0) split2 weights
    {
        long total = (long)DPROJ * (DM/4);
        mamba_split2<<<(unsigned)((total+255)/256), 256, 0, stream>>>(in_proj_w, wInS, DPROJ, DM);
        total = (long)DM * (DI/4);
        mamba_split2<<<(unsigned)((total+255)/256), 256, 0, stream>>>(out_proj_w, wOutS, DM, DI);
    }
    // 1) in_proj as 3 column-range GEMMs (split-bf16 MFMA, A converted on the fly)
    {
        dim3 gz(DI/128, BL/128);      // z: rows [0, 2048)
        gemm_asplit<<<gz, 256, 0, stream>>>(u, DM, wInS, DI, zbuf, DI, DM);
        dim3 gx(CONVD/128, BL/128);   // xBC: rows [2048, 4352)
        gemm_asplit<<<gx, 256, 0, stream>>>(u, DM, wInS + (long)DI*2*DM, CONVD, xpre, CONVD, DM);
        dim3 gd(1, BL/128);           // dt: rows [4352, 4384), N-guarded
        gemm_asplit<<<gd, 256, 0, stream>>>(u, DM, wInS + (long)(DI+CONVD)*2*DM, NH, dtraw, NH, DM);
    }
    // 2) conv + silu
    {
        long total = (long)BL*(CONVD/4);
        mamba_conv_silu<<<(unsigned)((total+255)/256), 256, 0, stream>>>(xpre, conv_w, conv_b, xBC);
    }
    // 3) dt softplus + cumsum
    mamba_dt_cumsum<<<BATCH*NC*NH, CHK, 0, stream>>>(dtraw, dt_bias, A_log, dtb, acs);
    // 4) CB batched GEMM (fp32, small)
    {
        dim3 grid(CHK/64, CHK/64, BATCH*NC);
        mamba_gemm_nt<64,64,16,4,4><<<grid, 256, 0, stream>>>(
            xBC + DI + DSTATE, xBC + DI, CBb,
            CHK, CHK, DSTATE, CONVD, CONVD, CHK,
            (long)CHK*CONVD, (long)CHK*CONVD, (long)CHK*CHK);
    }
    // 5) per-chunk states (into d_out)
    mamba_states<<<BATCH*NC*NH, 256, 0, stream>>>(xBC, dtb, acs, stb);
    // 6) inter-chunk scan, in-place (states -> prevs)
    {
        long total = (long)BATCH*NH*DH*DSTATE;
        mamba_scan<<<(unsigned)((total+255)/256), 256, 0, stream>>>(stb, acs);
    }
    // 7) y (reads prevs from d_out, writes yb = xpre alias)
    {
        dim3 grid(CHK/64, BATCH*NC*NH);
        mamba_y<<<grid, 256, 0, stream>>>(xBC, CBb, dtb, acs, stb, Dp, yb);
    }
    // 8) gate + RMSNorm in place
    mamba_gate_norm<<<BL, 256, 0, stream>>>(zbuf, norm_w, yb);
    // 9) out_proj (split-bf16 MFMA, overwrites d_out)
    {
        dim3 grid(DM/128, BL/128);
        gemm_asplit<<<grid, 256, 0, stream>>>(yb, DI, wOutS, DM, out, DM, DI);
    }
}

// Round 7
// 916.068 us; speedup vs baseline: 1.5968x; 1.5968x over previous
//
#include <hip/hip_runtime.h>
#include <hip/hip_bf16.h>
#include <math.h>

// ---- problem dims ----
constexpr int BATCH = 2;
constexpr int SEQ   = 4096;
constexpr int DM    = 1024;   // DIM_MODEL
constexpr int DSTATE= 128;
constexpr int DH    = 64;     // head dim
constexpr int NH    = 32;     // heads
constexpr int CHK   = 256;    // chunk
constexpr int DI    = 2048;   // DIM_INNER = DIM_SSD
constexpr int DPROJ = 4384;   // 2*DI + 2*DSTATE + NH
constexpr int CONVD = 2304;   // DI + 2*DSTATE
constexpr int NC    = SEQ / CHK;     // 16
constexpr int BL    = BATCH * SEQ;   // 8192

// ---- workspace layout (bytes); total ~244 MiB ----
constexpr long SZ_Z    = (long)BL*DI*4;
constexpr long SZ_XPRE = (long)BL*CONVD*4;
constexpr long SZ_DTRW = (long)BL*NH*4;
constexpr long SZ_XBC  = (long)BL*CONVD*4;
constexpr long SZ_DT   = (long)BL*NH*4;
constexpr long SZ_ACS  = (long)BL*NH*4;
constexpr long SZ_CB   = (long)BATCH*NC*CHK*CHK*4;
constexpr long SZ_WIS  = (long)DPROJ*2*DM*2;
constexpr long SZ_WOS  = (long)DM*2*DI*2;

constexpr long OFF_Z    = 0;
constexpr long OFF_XPRE = OFF_Z    + SZ_Z;
constexpr long OFF_DTRW = OFF_XPRE + SZ_XPRE;
constexpr long OFF_XBC  = OFF_DTRW + SZ_DTRW;
constexpr long OFF_DT   = OFF_XBC  + SZ_XBC;
constexpr long OFF_ACS  = OFF_DT   + SZ_DT;
constexpr long OFF_CB   = OFF_ACS  + SZ_ACS;
constexpr long OFF_WIS  = OFF_CB   + SZ_CB;
constexpr long OFF_WOS  = OFF_WIS  + SZ_WIS;

using bf16x8 = __attribute__((ext_vector_type(8))) short;
using us8    = __attribute__((ext_vector_type(8))) unsigned short;
using f32x4  = __attribute__((ext_vector_type(4))) float;

__device__ __forceinline__ unsigned short f2bf(float x) {
    __hip_bfloat16 h = __float2bfloat16(x);   // HW cvt (RNE)
    return *reinterpret_cast<unsigned short*>(&h);
}
__device__ __forceinline__ float bf2f(unsigned short s) {
    return __uint_as_float((unsigned)s << 16);
}

// convert 8 f32 -> hi/lo bf16 vectors
__device__ __forceinline__ void cvt8(const float4 a, const float4 b, us8& h, us8& l) {
    float vv[8] = {a.x, a.y, a.z, a.w, b.x, b.y, b.z, b.w};
    us8 hh, ll;
#pragma unroll
    for (int j = 0; j < 8; ++j) {
        hh[j] = f2bf(vv[j]);
        ll[j] = f2bf(vv[j] - bf2f(hh[j]));
    }
    h = hh; l = ll;
}

// ======================================================================
// split2 (weights only): src f32 [rows][K] -> dst bf16 [rows][2K]=[hi|lo]
// ======================================================================
__global__ void mamba_split2(const float* __restrict__ src, unsigned short* __restrict__ dst,
                             long rows, int K)
{
    long idx = (long)blockIdx.x * blockDim.x + threadIdx.x;
    long total = rows * (K / 4);
    if (idx >= total) return;
    long r  = idx / (K / 4);
    int  kq = (int)(idx % (K / 4)) * 4;

    float4 v = *reinterpret_cast<const float4*>(&src[r * (long)K + kq]);
    float vv[4] = {v.x, v.y, v.z, v.w};
    unsigned short hi[4], lo[4];
#pragma unroll
    for (int j = 0; j < 4; ++j) {
        hi[j] = f2bf(vv[j]);
        lo[j] = f2bf(vv[j] - bf2f(hi[j]));
    }
    unsigned short* dd = dst + r * (long)(2 * K);
    *reinterpret_cast<ushort4*>(&dd[kq])     = make_ushort4(hi[0], hi[1], hi[2], hi[3]);
    *reinterpret_cast<ushort4*>(&dd[K + kq]) = make_ushort4(lo[0], lo[1], lo[2], lo[3]);
}

// ======================================================================
// split-bf16 MFMA GEMM (NT) — unchanged from passing round-5 version
// ======================================================================
__launch_bounds__(256, 2)
__global__ void gemm_asplit(const float* __restrict__ A, int lda,
                            const unsigned short* __restrict__ Bs, int Nrows,
                            float* __restrict__ C, int ldc, int Kr)
{
    constexpr int LK = 40;
    __shared__ unsigned short sAhi[128 * LK];
    __shared__ unsigned short sAlo[128 * LK];
    __shared__ unsigned short sBhi[128 * LK];
    __shared__ unsigned short sBlo[128 * LK];

    const int tid  = threadIdx.x;
    const int lane = tid & 63;
    const int wave = tid >> 6;
    const int wr = wave >> 1, wc = wave & 1;
    const long m0 = (long)blockIdx.y * 128;
    const long n0 = (long)blockIdx.x * 128;
    const int ldb = 2 * Kr;

    const int row  = tid >> 1;
    const int col0 = (tid & 1) * 16;
    const float* Ap = A + (m0 + row) * (long)lda + col0;
    const long brow = n0 + row;
    const bool bok  = brow < Nrows;
    const unsigned short* Bph = Bs + brow * (long)ldb + col0;
    const unsigned short* Bpl = Bs + brow * (long)ldb + Kr + col0;
    unsigned short* wAh = &sAhi[row * LK + col0];
    unsigned short* wAl = &sAlo[row * LK + col0];
    unsigned short* wBh = &sBhi[row * LK + col0];
    unsigned short* wBl = &sBlo[row * LK + col0];

    const int fr  = lane & 15;
    const int fkb = (lane >> 4) * 8;

    f32x4 acc[4][4];
#pragma unroll
    for (int i = 0; i < 4; ++i)
#pragma unroll
        for (int j = 0; j < 4; ++j) acc[i][j] = (f32x4){0.f, 0.f, 0.f, 0.f};

    const int4 zero4 = make_int4(0, 0, 0, 0);
    float4 fa0 = *reinterpret_cast<const float4*>(Ap + 0);
    float4 fa1 = *reinterpret_cast<const float4*>(Ap + 4);
    float4 fa2 = *reinterpret_cast<const float4*>(Ap + 8);
    float4 fa3 = *reinterpret_cast<const float4*>(Ap + 12);
    int4 rbh0 = bok ? *reinterpret_cast<const int4*>(Bph + 0) : zero4;
    int4 rbh1 = bok ? *reinterpret_cast<const int4*>(Bph + 8) : zero4;
    int4 rbl0 = bok ? *reinterpret_cast<const int4*>(Bpl + 0) : zero4;
    int4 rbl1 = bok ? *reinterpret_cast<const int4*>(Bpl + 8) : zero4;
    us8 cah0, cah1, cal0, cal1;
    cvt8(fa0, fa1, cah0, cal0);
    cvt8(fa2, fa3, cah1, cal1);

    for (int kt = 0; kt < Kr; kt += 32) {
        *reinterpret_cast<us8*>(wAh)     = cah0;
        *reinterpret_cast<us8*>(wAh + 8) = cah1;
        *reinterpret_cast<us8*>(wAl)     = cal0;
        *reinterpret_cast<us8*>(wAl + 8) = cal1;
        *reinterpret_cast<int4*>(wBh)     = rbh0;
        *reinterpret_cast<int4*>(wBh + 8) = rbh1;
        *reinterpret_cast<int4*>(wBl)     = rbl0;
        *reinterpret_cast<int4*>(wBl + 8) = rbl1;
        __syncthreads();

        const int kn = kt + 32;
        if (kn < Kr) {
            fa0 = *reinterpret_cast<const float4*>(Ap + kn + 0);
            fa1 = *reinterpret_cast<const float4*>(Ap + kn + 4);
            fa2 = *reinterpret_cast<const float4*>(Ap + kn + 8);
            fa3 = *reinterpret_cast<const float4*>(Ap + kn + 12);
            rbh0 = bok ? *reinterpret_cast<const int4*>(Bph + kn + 0) : zero4;
            rbh1 = bok ? *reinterpret_cast<const int4*>(Bph + kn + 8) : zero4;
            rbl0 = bok ? *reinterpret_cast<const int4*>(Bpl + kn + 0) : zero4;
            rbl1 = bok ? *reinterpret_cast<const int4*>(Bpl + kn + 8) : zero4;
        }

        bf16x8 ah[4], al[4], bh[4], bl[4];
#pragma unroll
        for (int mi = 0; mi < 4; ++mi) {
            ah[mi] = *reinterpret_cast<const bf16x8*>(&sAhi[(wr * 64 + mi * 16 + fr) * LK + fkb]);
            al[mi] = *reinterpret_cast<const bf16x8*>(&sAlo[(wr * 64 + mi * 16 + fr) * LK + fkb]);
        }
#pragma unroll
        for (int ni = 0; ni < 4; ++ni) {
            bh[ni] = *reinterpret_cast<const bf16x8*>(&sBhi[(wc * 64 + ni * 16 + fr) * LK + fkb]);
            bl[ni] = *reinterpret_cast<const bf16x8*>(&sBlo[(wc * 64 + ni * 16 + fr) * LK + fkb]);
        }
#pragma unroll
        for (int mi = 0; mi < 4; ++mi)
#pragma unroll
            for (int ni = 0; ni < 4; ++ni) {
                acc[mi][ni] = __builtin_amdgcn_mfma_f32_16x16x32_bf16(ah[mi], bh[ni], acc[mi][ni], 0, 0, 0);
                acc[mi][ni] = __builtin_amdgcn_mfma_f32_16x16x32_bf16(al[mi], bh[ni], acc[mi][ni], 0, 0, 0);
                acc[mi][ni] = __builtin_amdgcn_mfma_f32_16x16x32_bf16(ah[mi], bl[ni], acc[mi][ni], 0, 0, 0);
            }

        if (kn < Kr) {
            cvt8(fa0, fa1, cah0, cal0);
            cvt8(fa2, fa3, cah1, cal1);
        }
        __syncthreads();
    }

    const int crow = (lane >> 4) * 4;
#pragma unroll
    for (int mi = 0; mi < 4; ++mi) {
        long gm = m0 + wr * 64 + mi * 16 + crow;
#pragma unroll
        for (int ni = 0; ni < 4; ++ni) {
            long gn = n0 + wc * 64 + ni * 16 + fr;
            if (gn < Nrows) {
#pragma unroll
                for (int j = 0; j < 4; ++j)
                    C[(gm + j) * (long)ldc + gn] = acc[mi][ni][j];
            }
        }
    }
}

// ======================================================================
// fp32 GEMM (NT) — small CB batched GEMM only (unchanged)
// ======================================================================
template<int BM,int BN,int BK,int TM,int TN>
__launch_bounds__(256)
__global__ void mamba_gemm_nt(const float* __restrict__ A, const float* __restrict__ Bw,
                              float* __restrict__ C,
                              int M, int N, int K, int lda, int ldb, int ldc,
                              long strideA, long strideB, long strideC)
{
    constexpr int NT = 256;
    const int batch = blockIdx.z;
    A  += (long)batch * strideA;
    Bw += (long)batch * strideB;
    C  += (long)batch * strideC;
    const int m0 = blockIdx.y * BM;
    const int n0 = blockIdx.x * BN;

    __shared__ float sA[BK][BM+4];
    __shared__ float sB[BK][BN+4];

    const int tid = threadIdx.x;
    const int tx  = tid % (BN/TN);
    const int ty  = tid / (BN/TN);

    float acc[TM][TN];
#pragma unroll
    for (int i = 0; i < TM; ++i)
#pragma unroll
        for (int j = 0; j < TN; ++j) acc[i][j] = 0.f;

    constexpr int AV = (BM*BK)/(NT*4);
    constexpr int BV = (BN*BK)/(NT*4);
    static_assert(AV >= 1 && BV >= 1, "tile too small");

    for (int k0 = 0; k0 < K; k0 += BK) {
#pragma unroll
        for (int v = 0; v < AV; ++v) {
            int idx = tid + v*NT;
            int m   = idx / (BK/4);
            int kq  = idx % (BK/4);
            int gm  = m0 + m;
            float4 val = make_float4(0.f,0.f,0.f,0.f);
            if (gm < M) val = *reinterpret_cast<const float4*>(&A[(long)gm*lda + k0 + kq*4]);
            sA[kq*4+0][m] = val.x; sA[kq*4+1][m] = val.y;
            sA[kq*4+2][m] = val.z; sA[kq*4+3][m] = val.w;
        }
#pragma unroll
        for (int v = 0; v < BV; ++v) {
            int idx = tid + v*NT;
            int n   = idx / (BK/4);
            int kq  = idx % (BK/4);
            int gn  = n0 + n;
            float4 val = make_float4(0.f,0.f,0.f,0.f);
            if (gn < N) val = *reinterpret_cast<const float4*>(&Bw[(long)gn*ldb + k0 + kq*4]);
            sB[kq*4+0][n] = val.x; sB[kq*4+1][n] = val.y;
            sB[kq*4+2][n] = val.z; sB[kq*4+3][n] = val.w;
        }
        __syncthreads();
#pragma unroll
        for (int k = 0; k < BK; ++k) {
            float ar[TM], br[TN];
#pragma unroll
            for (int i = 0; i < TM; ++i) ar[i] = sA[k][ty*TM+i];
#pragma unroll
            for (int j = 0; j < TN; ++j) br[j] = sB[k][tx*TN+j];
#pragma unroll
            for (int i = 0; i < TM; ++i)
#pragma unroll
                for (int j = 0; j < TN; ++j) acc[i][j] += ar[i]*br[j];
        }
        __syncthreads();
    }

#pragma unroll
    for (int i = 0; i < TM; ++i) {
        int gm = m0 + ty*TM + i;
        if (gm >= M) continue;
#pragma unroll
        for (int j = 0; j < TN; ++j) {
            int gn = n0 + tx*TN + j;
            if (gn < N) C[(long)gm*ldc + gn] = acc[i][j];
        }
    }
}

// ======================================================================
// Depthwise causal conv (width 4) + SiLU (unchanged)
// ======================================================================
__global__ void mamba_conv_silu(const float* __restrict__ xpre,
                                const float* __restrict__ conv_w,
                                const float* __restrict__ conv_b,
                                float* __restrict__ xBC)
{
    long idx = (long)blockIdx.x * blockDim.x + threadIdx.x;
    if (idx >= (long)BL*(CONVD/4)) return;
    int ch4 = (int)(idx % (CONVD/4)) * 4;
    long bl = idx / (CONVD/4);
    int l = (int)(bl % SEQ);
    long brow = bl - l;

    float4 w0 = *reinterpret_cast<const float4*>(&conv_w[(ch4+0)*4]);
    float4 w1 = *reinterpret_cast<const float4*>(&conv_w[(ch4+1)*4]);
    float4 w2 = *reinterpret_cast<const float4*>(&conv_w[(ch4+2)*4]);
    float4 w3 = *reinterpret_cast<const float4*>(&conv_w[(ch4+3)*4]);
    float4 accv = *reinterpret_cast<const float4*>(&conv_b[ch4]);
    float acc[4] = {accv.x, accv.y, accv.z, accv.w};
    const float wk[4][4] = {{w0.x,w0.y,w0.z,w0.w},{w1.x,w1.y,w1.z,w1.w},
                            {w2.x,w2.y,w2.z,w2.w},{w3.x,w3.y,w3.z,w3.w}};
#pragma unroll
    for (int k = 0; k < 4; ++k) {
        int lk = l - 3 + k;
        if (lk >= 0) {
            float4 v = *reinterpret_cast<const float4*>(&xpre[(brow + lk)*CONVD + ch4]);
            acc[0] += wk[0][k]*v.x; acc[1] += wk[1][k]*v.y;
            acc[2] += wk[2][k]*v.z; acc[3] += wk[3][k]*v.w;
        }
    }
    float4 o;
    o.x = acc[0] / (1.f + expf(-acc[0]));
    o.y = acc[1] / (1.f + expf(-acc[1]));
    o.z = acc[2] / (1.f + expf(-acc[2]));
    o.w = acc[3] / (1.f + expf(-acc[3]));
    *reinterpret_cast<float4*>(&xBC[bl*CONVD + ch4]) = o;
}

// ======================================================================
// dt = softplus(dt_raw + bias); a = dt*A; inclusive cumsum per (b,c,h)
// ======================================================================
__global__ void mamba_dt_cumsum(const float* __restrict__ dtraw,
                                const float* __restrict__ dt_bias,
                                const float* __restrict__ A_log,
                                float* __restrict__ dt_o,
                                float* __restrict__ acs_o)
{
    int blk = blockIdx.x;           // bc*NH + h
    int h  = blk % NH;
    int bc = blk / NH;
    int j  = threadIdx.x;
    long bl = (long)bc*CHK + j;

    float raw = dtraw[bl*NH + h] + dt_bias[h];
    float dt  = (raw > 20.f) ? raw : log1pf(expf(raw));
    float A   = -expf(A_log[h]);
    float a   = dt * A;

    __shared__ float s[CHK];
    s[j] = a;
    __syncthreads();
    for (int off = 1; off < CHK; off <<= 1) {
        float v = (j >= off) ? s[j-off] : 0.f;
        __syncthreads();
        s[j] += v;
        __syncthreads();
    }
    dt_o [bl*NH + h] = dt;
    acs_o[bl*NH + h] = s[j];
}

// ======================================================================
// states (unchanged; writes into d_out)
// ======================================================================
__launch_bounds__(256)
__global__ void mamba_states(const float* __restrict__ xBC,
                             const float* __restrict__ dt,
                             const float* __restrict__ acs,
                             float* __restrict__ states)
{
    int blk = blockIdx.x;
    int h  = blk % NH;
    int bc = blk / NH;
    const int tid = threadIdx.x;
    const int tn = tid % 16;
    const int tp = tid / 16;

    __shared__ float sx[16][DH+1];
    __shared__ float sb[16][DSTATE+1];

    float acc[4][8];
#pragma unroll
    for (int i=0;i<4;++i)
#pragma unroll
        for (int j=0;j<8;++j) acc[i][j]=0.f;

    float acs_last = acs[((long)bc*CHK + CHK-1)*NH + h];

    for (int j0 = 0; j0 < CHK; j0 += 16) {
        {
            int r  = tid / 16;
            int cq = tid % 16;
            long bl = (long)bc*CHK + j0 + r;
            float4 v = *reinterpret_cast<const float4*>(&xBC[bl*CONVD + h*DH + cq*4]);
            float w = dt[bl*NH+h] * expf(acs_last - acs[bl*NH+h]);
            sx[r][cq*4+0]=v.x*w; sx[r][cq*4+1]=v.y*w;
            sx[r][cq*4+2]=v.z*w; sx[r][cq*4+3]=v.w*w;
        }
        {
#pragma unroll
            for (int t = 0; t < 2; ++t) {
                int idx = tid + t*256;
                int r  = idx / 32;
                int cq = idx % 32;
                long bl = (long)bc*CHK + j0 + r;
                float4 v = *reinterpret_cast<const float4*>(&xBC[bl*CONVD + DI + cq*4]);
                sb[r][cq*4+0]=v.x; sb[r][cq*4+1]=v.y;
                sb[r][cq*4+2]=v.z; sb[r][cq*4+3]=v.w;
            }
        }
        __syncthreads();
#pragma unroll
        for (int jj = 0; jj < 16; ++jj) {
            float xr[4], br[8];
#pragma unroll
            for (int i=0;i<4;++i) xr[i]=sx[jj][tp*4+i];
#pragma unroll
            for (int j=0;j<8;++j) br[j]=sb[jj][tn*8+j];
#pragma unroll
            for (int i=0;i<4;++i)
#pragma unroll
                for (int j=0;j<8;++j) acc[i][j] += xr[i]*br[j];
        }
        __syncthreads();
    }

    float* out = states + (long)blk * DH * DSTATE;
#pragma unroll
    for (int i=0;i<4;++i)
#pragma unroll
        for (int j=0;j<8;++j)
            out[(tp*4+i)*DSTATE + tn*8+j] = acc[i][j];
}

// ======================================================================
// inter-chunk scan, IN-PLACE (unchanged)
// ======================================================================
__global__ void mamba_scan(float* __restrict__ st,
                           const float* __restrict__ acs)
{
    long idx = (long)blockIdx.x * blockDim.x + threadIdx.x;
    if (idx >= (long)BATCH*NH*DH*DSTATE) return;
    int n = (int)(idx % DSTATE);
    int p = (int)((idx / DSTATE) % DH);
    int h = (int)((idx / ((long)DSTATE*DH)) % NH);
    int b = (int)( idx / ((long)DSTATE*DH*NH));

    float carry = 0.f;
    for (int c = 0; c < NC; ++c) {
        int bc = b*NC + c;
        long o = ((long)(bc*NH + h)*DH + p)*DSTATE + n;
        float s = st[o];
        st[o] = carry;
        float dchunk = expf(acs[((long)bc*CHK + CHK-1)*NH + h]);
        carry = carry*dchunk + s;
    }
}

// ======================================================================
// MFMA SSD y kernel. One block per (bc,h), 256 thr = 4 waves.
// acc = P @ x + Cs @ prevs^T;  y = acc + D*x
//   P[i][j]  = CB[i][j]*exp(ai-aj)*dt_j  (causal), split hi/lo bf16
//   Cs[i][n] = exp(ai)*C[i][n]           (folds the exp(acs_i) scale)
// Fragment maps identical to gemm_asplit (proven in round 5).
// Wave-interleaved rows: A-row base = mi*64 + w*16 (balances causal skip).
// ======================================================================
__launch_bounds__(256, 2)
__global__ void mamba_ssd_y(const float* __restrict__ xBC,
                            const float* __restrict__ CB,
                            const float* __restrict__ dt,
                            const float* __restrict__ acs,
                            const float* __restrict__ prevs,
                            const float* __restrict__ Dp,
                            float* __restrict__ y)
{
    constexpr int LK = 40;   // 32 + 8 pad shorts; rows 80B (16B-aligned)
    __shared__ unsigned short sPhi[256 * LK];
    __shared__ unsigned short sPlo[256 * LK];
    __shared__ unsigned short sXh[64 * LK];
    __shared__ unsigned short sXl[64 * LK];
    __shared__ float sAi[CHK];
    __shared__ float sDt[CHK];

    const int blk = blockIdx.x;       // bc*NH + h
    const int h  = blk % NH;
    const int bc = blk / NH;
    const int tid  = threadIdx.x;
    const int lane = tid & 63;
    const int w    = tid >> 6;
    const int fr   = lane & 15;
    const int fkb  = (lane >> 4) * 8;

    // stage acs, dt for this (bc,h)
    {
        long bl = (long)bc * CHK + tid;
        sAi[tid] = acs[bl * NH + h];
        sDt[tid] = dt [bl * NH + h];
    }
    __syncthreads();

    const float ai_r = sAi[tid];      // this thread's staging row i = tid
    const float ei_r = expf(ai_r);    // exp(acs_i) for Cs staging (<=1)

    f32x4 acc[4][4];
#pragma unroll
    for (int i = 0; i < 4; ++i)
#pragma unroll
        for (int j = 0; j < 4; ++j) acc[i][j] = (f32x4){0.f, 0.f, 0.f, 0.f};

    const float* CBrow = CB + (long)bc * CHK * CHK + (long)tid * CHK;

    // ---------------- part 1: intra-chunk, K = j (256) ----------------
    for (int j0 = 0; j0 < CHK; j0 += 32) {
        // stage P: thread owns row i=tid, 32 cols
        {
            const int i = tid;
#pragma unroll
            for (int q = 0; q < 8; ++q) {
                const int jb = j0 + q * 4;
                float4 cb = *reinterpret_cast<const float4*>(&CBrow[jb]);
                float vals[4] = {cb.x, cb.y, cb.z, cb.w};
                unsigned short hh[4], ll[4];
#pragma unroll
                for (int e = 0; e < 4; ++e) {
                    int j = jb + e;
                    float v = (j <= i) ? vals[e] * expf(ai_r - sAi[j]) * sDt[j] : 0.f;
                    hh[e] = f2bf(v);
                    ll[e] = f2bf(v - bf2f(hh[e]));
                }
                *reinterpret_cast<ushort4*>(&sPhi[i * LK + q * 4]) = make_ushort4(hh[0], hh[1], hh[2], hh[3]);
                *reinterpret_cast<ushort4*>(&sPlo[i * LK + q * 4]) = make_ushort4(ll[0], ll[1], ll[2], ll[3]);
            }
        }
        // stage x transposed [p][j] with XOR swizzle on the j 8-block
        {
            const int j  = tid >> 3;            // 0..31
            const int p8 = (tid & 7) * 8;
            const float* xr = &xBC[((long)bc * CHK + j0 + j) * CONVD + h * DH + p8];
            float4 a = *reinterpret_cast<const float4*>(xr);
            float4 b = *reinterpret_cast<const float4*>(xr + 4);
            float vv[8] = {a.x, a.y, a.z, a.w, b.x, b.y, b.z, b.w};
#pragma unroll
            for (int e = 0; e < 8; ++e) {
                const int p  = p8 + e;
                const int js = j ^ ((((p >> 3) & 3)) << 3);
                unsigned short hh = f2bf(vv[e]);
                sXh[p * LK + js] = hh;
                sXl[p * LK + js] = f2bf(vv[e] - bf2f(hh));
            }
        }
        __syncthreads();
        // MFMA: acc += P (hi+lo) @ x (hi+lo), 3-term split
        {
            bf16x8 xh[4], xl[4];
#pragma unroll
            for (int ni = 0; ni < 4; ++ni) {
                const int xr_ = ni * 16 + fr;
                const int ks  = fkb ^ ((((xr_ >> 3) & 3)) << 3);
                xh[ni] = *reinterpret_cast<const bf16x8*>(&sXh[xr_ * LK + ks]);
                xl[ni] = *reinterpret_cast<const bf16x8*>(&sXl[xr_ * LK + ks]);
            }
#pragma unroll
            for (int mi = 0; mi < 4; ++mi) {
                const int rbase = mi * 64 + w * 16;
                if (j0 <= rbase + 15) {          // causal: else P rows all zero
                    const int r = rbase + fr;
                    bf16x8 ph = *reinterpret_cast<const bf16x8*>(&sPhi[r * LK + fkb]);
                    bf16x8 pl = *reinterpret_cast<const bf16x8*>(&sPlo[r * LK + fkb]);
#pragma unroll
                    for (int ni = 0; ni < 4; ++ni) {
                        acc[mi][ni] = __builtin_amdgcn_mfma_f32_16x16x32_bf16(ph, xh[ni], acc[mi][ni], 0, 0, 0);
                        acc[mi][ni] = __builtin_amdgcn_mfma_f32_16x16x32_bf16(pl, xh[ni], acc[mi][ni], 0, 0, 0);
                        acc[mi][ni] = __builtin_amdgcn_mfma_f32_16x16x32_bf16(ph, xl[ni], acc[mi][ni], 0, 0, 0);
                    }
                }
            }
        }
        __syncthreads();
    }

    // ---------------- part 2: inter-chunk, K = n (128) ----------------
    for (int n0 = 0; n0 < DSTATE; n0 += 32) {
        // stage Cs = exp(ai)*C: thread owns row i=tid, 32 cols
        {
            const float* Crow = &xBC[((long)bc * CHK + tid) * CONVD + DI + DSTATE + n0];
#pragma unroll
            for (int q = 0; q < 8; ++q) {
                float4 c = *reinterpret_cast<const float4*>(&Crow[q * 4]);
                float vals[4] = {c.x * ei_r, c.y * ei_r, c.z * ei_r, c.w * ei_r};
                unsigned short hh[4], ll[4];
#pragma unroll
                for (int e = 0; e < 4; ++e) {
                    hh[e] = f2bf(vals[e]);
                    ll[e] = f2bf(vals[e] - bf2f(hh[e]));
                }
                *reinterpret_cast<ushort4*>(&sPhi[tid * LK + q * 4]) = make_ushort4(hh[0], hh[1], hh[2], hh[3]);
                *reinterpret_cast<ushort4*>(&sPlo[tid * LK + q * 4]) = make_ushort4(ll[0], ll[1], ll[2], ll[3]);
            }
        }
        // stage prevs [p][n] (natural layout, same swizzle on n 8-block)
        {
            const int p  = tid >> 2;            // 0..63
            const int n8 = (tid & 3) * 8;
            const float* pr = &prevs[((long)blk * DH + p) * DSTATE + n0 + n8];
            float4 a = *reinterpret_cast<const float4*>(pr);
            float4 b = *reinterpret_cast<const float4*>(pr + 4);
            us8 hh, ll;
            cvt8(a, b, hh, ll);
            const int ns = n8 ^ ((((p >> 3) & 3)) << 3);
            *reinterpret_cast<us8*>(&sXh[p * LK + ns]) = hh;
            *reinterpret_cast<us8*>(&sXl[p * LK + ns]) = ll;
        }
        __syncthreads();
        {
            bf16x8 vh[4], vl[4];
#pragma unroll
            for (int ni = 0; ni < 4; ++ni) {
                const int xr_ = ni * 16 + fr;
                const int ks  = fkb ^ ((((xr_ >> 3) & 3)) << 3);
                vh[ni] = *reinterpret_cast<const bf16x8*>(&sXh[xr_ * LK + ks]);
                vl[ni] = *reinterpret_cast<const bf16x8*>(&sXl[xr_ * LK + ks]);
            }
#pragma unroll
            for (int mi = 0; mi < 4; ++mi) {
                const int r = mi * 64 + w * 16 + fr;
                bf16x8 ch = *reinterpret_cast<const bf16x8*>(&sPhi[r * LK + fkb]);
                bf16x8 cl = *reinterpret_cast<const bf16x8*>(&sPlo[r * LK + fkb]);
#pragma unroll
                for (int ni = 0; ni < 4; ++ni) {
                    acc[mi][ni] = __builtin_amdgcn_mfma_f32_16x16x32_bf16(ch, vh[ni], acc[mi][ni], 0, 0, 0);
                    acc[mi][ni] = __builtin_amdgcn_mfma_f32_16x16x32_bf16(cl, vh[ni], acc[mi][ni], 0, 0, 0);
                    acc[mi][ni] = __builtin_amdgcn_mfma_f32_16x16x32_bf16(ch, vl[ni], acc[mi][ni], 0, 0, 0);
                }
            }
        }
        __syncthreads();
    }

    // ---------------- epilogue: + D*x, store ----------------
    const float Dh = Dp[h];
    const int crow = (lane >> 4) * 4;
#pragma unroll
    for (int mi = 0; mi < 4; ++mi) {
        const int ib = mi * 64 + w * 16 + crow;
#pragma unroll
        for (int e = 0; e < 4; ++e) {
            const long bl = (long)bc * CHK + ib + e;
#pragma unroll
            for (int ni = 0; ni < 4; ++ni) {
                const int p = ni * 16 + fr;
                float xv = xBC[bl * CONVD + h * DH + p];
                y[bl * DI + h * DH + p] = acc[mi][ni][e] + Dh * xv;
            }
        }
    }
}

// ======================================================================
// gate + RMSNorm, IN-PLACE on y (unchanged)
// ======================================================================
__launch_bounds__(256)
__global__ void mamba_gate_norm(const float* __restrict__ zbuf,
                                const float* __restrict__ norm_w,
                                float* __restrict__ y)
{
    long bl = blockIdx.x;
    const float* zrow = zbuf + bl*DI;
    float* yrow = y + bl*DI;
    const int base = threadIdx.x * 8;

    float vals[8];
    float ss = 0.f;
#pragma unroll
    for (int half = 0; half < 2; ++half) {
        float4 zv = *reinterpret_cast<const float4*>(&zrow[base + half*4]);
        float4 yv = *reinterpret_cast<const float4*>(&yrow[base + half*4]);
        float zz[4] = {zv.x, zv.y, zv.z, zv.w};
        float yy[4] = {yv.x, yv.y, yv.z, yv.w};
#pragma unroll
        for (int t = 0; t < 4; ++t) {
            float v = yy[t] * (zz[t] / (1.f + expf(-zz[t])));
            vals[half*4+t] = v;
            ss += v*v;
        }
    }
#pragma unroll
    for (int o = 1; o < 64; o <<= 1) ss += __shfl_xor(ss, o, 64);

    __shared__ float red[4];
    int wid = threadIdx.x >> 6;
    if ((threadIdx.x & 63) == 0) red[wid] = ss;
    __syncthreads();
    ss = red[0] + red[1] + red[2] + red[3];
    float scale = rsqrtf(ss / DI + 1e-5f);

#pragma unroll
    for (int half = 0; half < 2; ++half) {
        float4 nw = *reinterpret_cast<const float4*>(&norm_w[base + half*4]);
        float4 o;
        o.x = vals[half*4+0] * scale * nw.x;
        o.y = vals[half*4+1] * scale * nw.y;
        o.z = vals[half*4+2] * scale * nw.z;
        o.w = vals[half*4+3] * scale * nw.w;
        *reinterpret_cast<float4*>(&yrow[base + half*4]) = o;
    }
}

// ======================================================================
extern "C" void kernel_launch(void* const* d_in, const int* in_sizes, int n_in,
                              void* d_out, int out_size, void* d_ws, size_t ws_size,
                              hipStream_t stream)
{
    const float* u         = (const float*)d_in[0];
    const float* in_proj_w = (const float*)d_in[1];
    const float* conv_w    = (const float*)d_in[2];
    const float* conv_b    = (const float*)d_in[3];
    const float* dt_bias   = (const float*)d_in[4];
    const float* A_log     = (const float*)d_in[5];
    const float* Dp        = (const float*)d_in[6];
    const float* norm_w    = (const float*)d_in[7];
    const float* out_proj_w= (const float*)d_in[8];
    float* out = (float*)d_out;

    char* ws = (char*)d_ws;
    float* zbuf  = (float*)(ws + OFF_Z);
    float* xpre  = (float*)(ws + OFF_XPRE);
    float* yb    = xpre;                       // alias: xpre dead after conv
    float* dtraw = (float*)(ws + OFF_DTRW);
    float* xBC   = (float*)(ws + OFF_XBC);
    float* dtb   = (float*)(ws + OFF_DT);
    float* acs   = (float*)(ws + OFF_ACS);
    float* CBb   = (float*)(ws + OFF_CB);
    unsigned short* wInS  = (unsigned short*)(ws + OFF_WIS);
    unsigned short* wOutS = (unsigned short*)(ws + OFF_WOS);
    float* stb = out;                          // states/prevs live in d_out

    // 0) split2 weights
    {
        long total = (long)DPROJ * (DM/4);
        mamba_split2<<<(unsigned)((total+255)/256), 256, 0, stream>>>(in_proj_w, wInS, DPROJ, DM);
        total = (long)DM * (DI/4);
        mamba_split2<<<(unsigned)((total+255)/256), 256, 0, stream>>>(out_proj_w, wOutS, DM, DI);
    }
    // 1) in_proj as 3 column-range GEMMs
    {
        dim3 gz(DI/128, BL/128);
        gemm_asplit<<<gz, 256, 0, stream>>>(u, DM, wInS, DI, zbuf, DI, DM);
        dim3 gx(CONVD/128, BL/128);
        gemm_asplit<<<gx, 256, 0, stream>>>(u, DM, wInS + (long)DI*2*DM, CONVD, xpre, CONVD, DM);
        dim3 gd(1, BL/128);
        gemm_asplit<<<gd, 256, 0, stream>>>(u, DM, wInS + (long)(DI+CONVD)*2*DM, NH, dtraw, NH, DM);
    }
    // 2) conv + silu
    {
        long total = (long)BL*(CONVD/4);
        mamba_conv_silu<<<(unsigned)((total+255)/256), 256, 0, stream>>>(xpre, conv_w, conv_b, xBC);
    }
    // 3) dt softplus + cumsum
    mamba_dt_cumsum<<<BATCH*NC*NH, CHK, 0, stream>>>(dtraw, dt_bias, A_log, dtb, acs);
    // 4) CB batched GEMM (fp32, small)
    {
        dim3 grid(CHK/64, CHK/64, BATCH*NC);
        mamba_gemm_nt<64,64,16,4,4><<<grid, 256, 0, stream>>>(
            xBC + DI + DSTATE, xBC + DI, CBb,
            CHK, CHK, DSTATE, CONVD, CONVD, CHK,
            (long)CHK*CONVD, (long)CHK*CONVD, (long)CHK*CHK);
    }
    // 5) per-chunk states (into d_out)
    mamba_states<<<BATCH*NC*NH, 256, 0, stream>>>(xBC, dtb, acs, stb);
    // 6) inter-chunk scan, in-place
    {
        long total = (long)BATCH*NH*DH*DSTATE;
        mamba_scan<<<(unsigned)((total+255)/256), 256, 0, stream>>>(stb, acs);
    }
    // 7) y via MFMA (intra + inter + D skip)
    mamba_ssd_y<<<BATCH*NC*NH, 256, 0, stream>>>(xBC, CBb, dtb, acs, stb, Dp, yb);
    // 8) gate + RMSNorm in place
    mamba_gate_norm<<<BL, 256, 0, stream>>>(zbuf, norm_w, yb);
    // 9) out_proj (split-bf16 MFMA, overwrites d_out)
    {
        dim3 grid(DM/128, BL/128);
        gemm_asplit<<<grid, 256, 0, stream>>>(yb, DI, wOutS, DM, out, DM, DI);
    }
}

// Round 9
// 890.838 us; speedup vs baseline: 1.6420x; 1.0283x over previous
//
#include <hip/hip_runtime.h>
#include <hip/hip_bf16.h>
#include <math.h>

// ---- problem dims ----
constexpr int BATCH = 2;
constexpr int SEQ   = 4096;
constexpr int DM    = 1024;   // DIM_MODEL
constexpr int DSTATE= 128;
constexpr int DH    = 64;     // head dim
constexpr int NH    = 32;     // heads
constexpr int CHK   = 256;    // chunk
constexpr int DI    = 2048;   // DIM_INNER = DIM_SSD
constexpr int DPROJ = 4384;   // 2*DI + 2*DSTATE + NH
constexpr int CONVD = 2304;   // DI + 2*DSTATE
constexpr int NC    = SEQ / CHK;     // 16
constexpr int BL    = BATCH * SEQ;   // 8192

// ---- workspace layout (bytes); total ~244 MiB ----
// yb (BL*DI*4) aliases xpre: xpre dead after conv. gate_norm converts yb
// in place to split2 bf16 (same byte size). uS (u split2 bf16, 33.55MB)
// lives in d_out (dead until mamba_states overwrites it with states).
constexpr long SZ_Z    = (long)BL*DI*4;
constexpr long SZ_XPRE = (long)BL*CONVD*4;
constexpr long SZ_DTRW = (long)BL*NH*4;
constexpr long SZ_XBC  = (long)BL*CONVD*4;
constexpr long SZ_DT   = (long)BL*NH*4;
constexpr long SZ_ACS  = (long)BL*NH*4;
constexpr long SZ_CB   = (long)BATCH*NC*CHK*CHK*4;
constexpr long SZ_WIS  = (long)DPROJ*2*DM*2;
constexpr long SZ_WOS  = (long)DM*2*DI*2;

constexpr long OFF_Z    = 0;
constexpr long OFF_XPRE = OFF_Z    + SZ_Z;
constexpr long OFF_DTRW = OFF_XPRE + SZ_XPRE;
constexpr long OFF_XBC  = OFF_DTRW + SZ_DTRW;
constexpr long OFF_DT   = OFF_XBC  + SZ_XBC;
constexpr long OFF_ACS  = OFF_DT   + SZ_DT;
constexpr long OFF_CB   = OFF_ACS  + SZ_ACS;
constexpr long OFF_WIS  = OFF_CB   + SZ_CB;
constexpr long OFF_WOS  = OFF_WIS  + SZ_WIS;

using bf16x8 = __attribute__((ext_vector_type(8))) short;
using us8    = __attribute__((ext_vector_type(8))) unsigned short;
using f32x4  = __attribute__((ext_vector_type(4))) float;

__device__ __forceinline__ unsigned short f2bf(float x) {
    __hip_bfloat16 h = __float2bfloat16(x);   // HW cvt (RNE)
    return *reinterpret_cast<unsigned short*>(&h);
}
__device__ __forceinline__ float bf2f(unsigned short s) {
    return __uint_as_float((unsigned)s << 16);
}

// convert 8 f32 -> hi/lo bf16 vectors
__device__ __forceinline__ void cvt8(const float4 a, const float4 b, us8& h, us8& l) {
    float vv[8] = {a.x, a.y, a.z, a.w, b.x, b.y, b.z, b.w};
    us8 hh, ll;
#pragma unroll
    for (int j = 0; j < 8; ++j) {
        hh[j] = f2bf(vv[j]);
        ll[j] = f2bf(vv[j] - bf2f(hh[j]));
    }
    h = hh; l = ll;
}

// ======================================================================
// split2: src f32 [rows][K] -> dst bf16 [rows][2K]=[hi|lo]
// ======================================================================
__global__ void mamba_split2(const float* __restrict__ src, unsigned short* __restrict__ dst,
                             long rows, int K)
{
    long idx = (long)blockIdx.x * blockDim.x + threadIdx.x;
    long total = rows * (K / 4);
    if (idx >= total) return;
    long r  = idx / (K / 4);
    int  kq = (int)(idx % (K / 4)) * 4;

    float4 v = *reinterpret_cast<const float4*>(&src[r * (long)K + kq]);
    float vv[4] = {v.x, v.y, v.z, v.w};
    unsigned short hi[4], lo[4];
#pragma unroll
    for (int j = 0; j < 4; ++j) {
        hi[j] = f2bf(vv[j]);
        lo[j] = f2bf(vv[j] - bf2f(hi[j]));
    }
    unsigned short* dd = dst + r * (long)(2 * K);
    *reinterpret_cast<ushort4*>(&dd[kq])     = make_ushort4(hi[0], hi[1], hi[2], hi[3]);
    *reinterpret_cast<ushort4*>(&dd[K + kq]) = make_ushort4(lo[0], lo[1], lo[2], lo[3]);
}

// ======================================================================
// split-bf16 MFMA GEMM (NT), BOTH operands pre-split bf16 [rows][2Kr]=[hi|lo].
// C[m][n] = sum_k A[m][k]*B[n][k] (fp32-accurate: Ah*Bh + Al*Bh + Ah*Bl).
// No conversion in the loop — pure load/ds_read/MFMA pipeline.
// M%128==0; grid.x covers ceil(N/128) with Nrows guard; Kr%32==0.
// 256 thr = 4 waves (2x2), each wave 64x64 via 4x4 frags of 16x16x32.
// ======================================================================
__launch_bounds__(256, 2)
__global__ void gemm_ssplit(const unsigned short* __restrict__ As,
                            const unsigned short* __restrict__ Bs, int Nrows,
                            float* __restrict__ C, int ldc, int Kr)
{
    constexpr int LK = 40;   // 32 + 8 pad shorts; rows 80B, slots 16B-aligned
    __shared__ unsigned short sAhi[128 * LK];
    __shared__ unsigned short sAlo[128 * LK];
    __shared__ unsigned short sBhi[128 * LK];
    __shared__ unsigned short sBlo[128 * LK];

    const int tid  = threadIdx.x;
    const int lane = tid & 63;
    const int wave = tid >> 6;
    const int wr = wave >> 1, wc = wave & 1;
    const long m0 = (long)blockIdx.y * 128;
    const long n0 = (long)blockIdx.x * 128;
    const int ldb = 2 * Kr;

    // staging: per seg-tile (128x32 shorts = 8KB) each thread owns 2 slots:
    // (row0, c0) and (row0+64, c0); row0=tid>>2, c0=(tid&3)*8 shorts.
    const int row0 = tid >> 2;
    const int c0   = (tid & 3) * 8;
    const unsigned short* pA0 = As + (m0 + row0)      * (long)ldb + c0;
    const unsigned short* pA1 = As + (m0 + row0 + 64) * (long)ldb + c0;
    const long br0 = n0 + row0, br1 = n0 + row0 + 64;
    const bool bok0 = br0 < Nrows, bok1 = br1 < Nrows;
    const unsigned short* pB0 = Bs + br0 * (long)ldb + c0;
    const unsigned short* pB1 = Bs + br1 * (long)ldb + c0;
    unsigned short* wA0 = &sAhi[ row0       * LK + c0];
    unsigned short* wA1 = &sAhi[(row0 + 64) * LK + c0];
    unsigned short* wB0 = &sBhi[ row0       * LK + c0];
    unsigned short* wB1 = &sBhi[(row0 + 64) * LK + c0];
    unsigned short* wA0l = &sAlo[ row0       * LK + c0];
    unsigned short* wA1l = &sAlo[(row0 + 64) * LK + c0];
    unsigned short* wB0l = &sBlo[ row0       * LK + c0];
    unsigned short* wB1l = &sBlo[(row0 + 64) * LK + c0];

    const int fr  = lane & 15;
    const int fkb = (lane >> 4) * 8;

    f32x4 acc[4][4];
#pragma unroll
    for (int i = 0; i < 4; ++i)
#pragma unroll
        for (int j = 0; j < 4; ++j) acc[i][j] = (f32x4){0.f, 0.f, 0.f, 0.f};

    const int4 zero4 = make_int4(0, 0, 0, 0);
    // prefetch tile 0: hi at +0, lo at +Kr
    int4 rah0 = *reinterpret_cast<const int4*>(pA0);
    int4 rah1 = *reinterpret_cast<const int4*>(pA1);
    int4 ral0 = *reinterpret_cast<const int4*>(pA0 + Kr);
    int4 ral1 = *reinterpret_cast<const int4*>(pA1 + Kr);
    int4 rbh0 = bok0 ? *reinterpret_cast<const int4*>(pB0) : zero4;
    int4 rbh1 = bok1 ? *reinterpret_cast<const int4*>(pB1) : zero4;
    int4 rbl0 = bok0 ? *reinterpret_cast<const int4*>(pB0 + Kr) : zero4;
    int4 rbl1 = bok1 ? *reinterpret_cast<const int4*>(pB1 + Kr) : zero4;

    for (int kt = 0; kt < Kr; kt += 32) {
        *reinterpret_cast<int4*>(wA0)  = rah0;
        *reinterpret_cast<int4*>(wA1)  = rah1;
        *reinterpret_cast<int4*>(wA0l) = ral0;
        *reinterpret_cast<int4*>(wA1l) = ral1;
        *reinterpret_cast<int4*>(wB0)  = rbh0;
        *reinterpret_cast<int4*>(wB1)  = rbh1;
        *reinterpret_cast<int4*>(wB0l) = rbl0;
        *reinterpret_cast<int4*>(wB1l) = rbl1;
        __syncthreads();

        const int kn = kt + 32;
        if (kn < Kr) {   // prefetch next K-tile; latency hidden under MFMA phase
            rah0 = *reinterpret_cast<const int4*>(pA0 + kn);
            rah1 = *reinterpret_cast<const int4*>(pA1 + kn);
            ral0 = *reinterpret_cast<const int4*>(pA0 + Kr + kn);
            ral1 = *reinterpret_cast<const int4*>(pA1 + Kr + kn);
            rbh0 = bok0 ? *reinterpret_cast<const int4*>(pB0 + kn) : zero4;
            rbh1 = bok1 ? *reinterpret_cast<const int4*>(pB1 + kn) : zero4;
            rbl0 = bok0 ? *reinterpret_cast<const int4*>(pB0 + Kr + kn) : zero4;
            rbl1 = bok1 ? *reinterpret_cast<const int4*>(pB1 + Kr + kn) : zero4;
        }

        bf16x8 ah[4], al[4], bh[4], bl[4];
#pragma unroll
        for (int mi = 0; mi < 4; ++mi) {
            ah[mi] = *reinterpret_cast<const bf16x8*>(&sAhi[(wr * 64 + mi * 16 + fr) * LK + fkb]);
            al[mi] = *reinterpret_cast<const bf16x8*>(&sAlo[(wr * 64 + mi * 16 + fr) * LK + fkb]);
        }
#pragma unroll
        for (int ni = 0; ni < 4; ++ni) {
            bh[ni] = *reinterpret_cast<const bf16x8*>(&sBhi[(wc * 64 + ni * 16 + fr) * LK + fkb]);
            bl[ni] = *reinterpret_cast<const bf16x8*>(&sBlo[(wc * 64 + ni * 16 + fr) * LK + fkb]);
        }
#pragma unroll
        for (int mi = 0; mi < 4; ++mi)
#pragma unroll
            for (int ni = 0; ni < 4; ++ni) {
                acc[mi][ni] = __builtin_amdgcn_mfma_f32_16x16x32_bf16(ah[mi], bh[ni], acc[mi][ni], 0, 0, 0);
                acc[mi][ni] = __builtin_amdgcn_mfma_f32_16x16x32_bf16(al[mi], bh[ni], acc[mi][ni], 0, 0, 0);
                acc[mi][ni] = __builtin_amdgcn_mfma_f32_16x16x32_bf16(ah[mi], bl[ni], acc[mi][ni], 0, 0, 0);
            }
        __syncthreads();
    }

    // epilogue: C/D layout col=lane&15, row=(lane>>4)*4+j  [m89-verified]
    const int crow = (lane >> 4) * 4;
#pragma unroll
    for (int mi = 0; mi < 4; ++mi) {
        long gm = m0 + wr * 64 + mi * 16 + crow;
#pragma unroll
        for (int ni = 0; ni < 4; ++ni) {
            long gn = n0 + wc * 64 + ni * 16 + fr;
            if (gn < Nrows) {
#pragma unroll
                for (int j = 0; j < 4; ++j)
                    C[(gm + j) * (long)ldc + gn] = acc[mi][ni][j];
            }
        }
    }
}

// ======================================================================
// fp32 GEMM (NT) — small CB batched GEMM only (unchanged)
// ======================================================================
template<int BM,int BN,int BK,int TM,int TN>
__launch_bounds__(256)
__global__ void mamba_gemm_nt(const float* __restrict__ A, const float* __restrict__ Bw,
                              float* __restrict__ C,
                              int M, int N, int K, int lda, int ldb, int ldc,
                              long strideA, long strideB, long strideC)
{
    constexpr int NT = 256;
    const int batch = blockIdx.z;
    A  += (long)batch * strideA;
    Bw += (long)batch * strideB;
    C  += (long)batch * strideC;
    const int m0 = blockIdx.y * BM;
    const int n0 = blockIdx.x * BN;

    __shared__ float sA[BK][BM+4];
    __shared__ float sB[BK][BN+4];

    const int tid = threadIdx.x;
    const int tx  = tid % (BN/TN);
    const int ty  = tid / (BN/TN);

    float acc[TM][TN];
#pragma unroll
    for (int i = 0; i < TM; ++i)
#pragma unroll
        for (int j = 0; j < TN; ++j) acc[i][j] = 0.f;

    constexpr int AV = (BM*BK)/(NT*4);
    constexpr int BV = (BN*BK)/(NT*4);
    static_assert(AV >= 1 && BV >= 1, "tile too small");

    for (int k0 = 0; k0 < K; k0 += BK) {
#pragma unroll
        for (int v = 0; v < AV; ++v) {
            int idx = tid + v*NT;
            int m   = idx / (BK/4);
            int kq  = idx % (BK/4);
            int gm  = m0 + m;
            float4 val = make_float4(0.f,0.f,0.f,0.f);
            if (gm < M) val = *reinterpret_cast<const float4*>(&A[(long)gm*lda + k0 + kq*4]);
            sA[kq*4+0][m] = val.x; sA[kq*4+1][m] = val.y;
            sA[kq*4+2][m] = val.z; sA[kq*4+3][m] = val.w;
        }
#pragma unroll
        for (int v = 0; v < BV; ++v) {
            int idx = tid + v*NT;
            int n   = idx / (BK/4);
            int kq  = idx % (BK/4);
            int gn  = n0 + n;
            float4 val = make_float4(0.f,0.f,0.f,0.f);
            if (gn < N) val = *reinterpret_cast<const float4*>(&Bw[(long)gn*ldb + k0 + kq*4]);
            sB[kq*4+0][n] = val.x; sB[kq*4+1][n] = val.y;
            sB[kq*4+2][n] = val.z; sB[kq*4+3][n] = val.w;
        }
        __syncthreads();
#pragma unroll
        for (int k = 0; k < BK; ++k) {
            float ar[TM], br[TN];
#pragma unroll
            for (int i = 0; i < TM; ++i) ar[i] = sA[k][ty*TM+i];
#pragma unroll
            for (int j = 0; j < TN; ++j) br[j] = sB[k][tx*TN+j];
#pragma unroll
            for (int i = 0; i < TM; ++i)
#pragma unroll
                for (int j = 0; j < TN; ++j) acc[i][j] += ar[i]*br[j];
        }
        __syncthreads();
    }

#pragma unroll
    for (int i = 0; i < TM; ++i) {
        int gm = m0 + ty*TM + i;
        if (gm >= M) continue;
#pragma unroll
        for (int j = 0; j < TN; ++j) {
            int gn = n0 + tx*TN + j;
            if (gn < N) C[(long)gm*ldc + gn] = acc[i][j];
        }
    }
}

// ======================================================================
// Depthwise causal conv (width 4) + SiLU (unchanged)
// ======================================================================
__global__ void mamba_conv_silu(const float* __restrict__ xpre,
                                const float* __restrict__ conv_w,
                                const float* __restrict__ conv_b,
                                float* __restrict__ xBC)
{
    long idx = (long)blockIdx.x * blockDim.x + threadIdx.x;
    if (idx >= (long)BL*(CONVD/4)) return;
    int ch4 = (int)(idx % (CONVD/4)) * 4;
    long bl = idx / (CONVD/4);
    int l = (int)(bl % SEQ);
    long brow = bl - l;

    float4 w0 = *reinterpret_cast<const float4*>(&conv_w[(ch4+0)*4]);
    float4 w1 = *reinterpret_cast<const float4*>(&conv_w[(ch4+1)*4]);
    float4 w2 = *reinterpret_cast<const float4*>(&conv_w[(ch4+2)*4]);
    float4 w3 = *reinterpret_cast<const float4*>(&conv_w[(ch4+3)*4]);
    float4 accv = *reinterpret_cast<const float4*>(&conv_b[ch4]);
    float acc[4] = {accv.x, accv.y, accv.z, accv.w};
    const float wk[4][4] = {{w0.x,w0.y,w0.z,w0.w},{w1.x,w1.y,w1.z,w1.w},
                            {w2.x,w2.y,w2.z,w2.w},{w3.x,w3.y,w3.z,w3.w}};
#pragma unroll
    for (int k = 0; k < 4; ++k) {
        int lk = l - 3 + k;
        if (lk >= 0) {
            float4 v = *reinterpret_cast<const float4*>(&xpre[(brow + lk)*CONVD + ch4]);
            acc[0] += wk[0][k]*v.x; acc[1] += wk[1][k]*v.y;
            acc[2] += wk[2][k]*v.z; acc[3] += wk[3][k]*v.w;
        }
    }
    float4 o;
    o.x = acc[0] / (1.f + expf(-acc[0]));
    o.y = acc[1] / (1.f + expf(-acc[1]));
    o.z = acc[2] / (1.f + expf(-acc[2]));
    o.w = acc[3] / (1.f + expf(-acc[3]));
    *reinterpret_cast<float4*>(&xBC[bl*CONVD + ch4]) = o;
}

// ======================================================================
// dt = softplus(dt_raw + bias); a = dt*A; inclusive cumsum per (b,c,h)
// ======================================================================
__global__ void mamba_dt_cumsum(const float* __restrict__ dtraw,
                                const float* __restrict__ dt_bias,
                                const float* __restrict__ A_log,
                                float* __restrict__ dt_o,
                                float* __restrict__ acs_o)
{
    int blk = blockIdx.x;           // bc*NH + h
    int h  = blk % NH;
    int bc = blk / NH;
    int j  = threadIdx.x;
    long bl = (long)bc*CHK + j;

    float raw = dtraw[bl*NH + h] + dt_bias[h];
    float dt  = (raw > 20.f) ? raw : log1pf(expf(raw));
    float A   = -expf(A_log[h]);
    float a   = dt * A;

    __shared__ float s[CHK];
    s[j] = a;
    __syncthreads();
    for (int off = 1; off < CHK; off <<= 1) {
        float v = (j >= off) ? s[j-off] : 0.f;
        __syncthreads();
        s[j] += v;
        __syncthreads();
    }
    dt_o [bl*NH + h] = dt;
    acs_o[bl*NH + h] = s[j];
}

// ======================================================================
// states (unchanged; writes into d_out, overwriting the dead uS)
// ======================================================================
__launch_bounds__(256)
__global__ void mamba_states(const float* __restrict__ xBC,
                             const float* __restrict__ dt,
                             const float* __restrict__ acs,
                             float* __restrict__ states)
{
    int blk = blockIdx.x;
    int h  = blk % NH;
    int bc = blk / NH;
    const int tid = threadIdx.x;
    const int tn = tid % 16;
    const int tp = tid / 16;

    __shared__ float sx[16][DH+1];
    __shared__ float sb[16][DSTATE+1];

    float acc[4][8];
#pragma unroll
    for (int i=0;i<4;++i)
#pragma unroll
        for (int j=0;j<8;++j) acc[i][j]=0.f;

    float acs_last = acs[((long)bc*CHK + CHK-1)*NH + h];

    for (int j0 = 0; j0 < CHK; j0 += 16) {
        {
            int r  = tid / 16;
            int cq = tid % 16;
            long bl = (long)bc*CHK + j0 + r;
            float4 v = *reinterpret_cast<const float4*>(&xBC[bl*CONVD + h*DH + cq*4]);
            float w = dt[bl*NH+h] * expf(acs_last - acs[bl*NH+h]);
            sx[r][cq*4+0]=v.x*w; sx[r][cq*4+1]=v.y*w;
            sx[r][cq*4+2]=v.z*w; sx[r][cq*4+3]=v.w*w;
        }
        {
#pragma unroll
            for (int t = 0; t < 2; ++t) {
                int idx = tid + t*256;
                int r  = idx / 32;
                int cq = idx % 32;
                long bl = (long)bc*CHK + j0 + r;
                float4 v = *reinterpret_cast<const float4*>(&xBC[bl*CONVD + DI + cq*4]);
                sb[r][cq*4+0]=v.x; sb[r][cq*4+1]=v.y;
                sb[r][cq*4+2]=v.z; sb[r][cq*4+3]=v.w;
            }
        }
        __syncthreads();
#pragma unroll
        for (int jj = 0; jj < 16; ++jj) {
            float xr[4], br[8];
#pragma unroll
            for (int i=0;i<4;++i) xr[i]=sx[jj][tp*4+i];
#pragma unroll
            for (int j=0;j<8;++j) br[j]=sb[jj][tn*8+j];
#pragma unroll
            for (int i=0;i<4;++i)
#pragma unroll
                for (int j=0;j<8;++j) acc[i][j] += xr[i]*br[j];
        }
        __syncthreads();
    }

    float* out = states + (long)blk * DH * DSTATE;
#pragma unroll
    for (int i=0;i<4;++i)
#pragma unroll
        for (int j=0;j<8;++j)
            out[(tp*4+i)*DSTATE + tn*8+j] = acc[i][j];
}

// ======================================================================
// inter-chunk scan, IN-PLACE (unchanged)
// ======================================================================
__global__ void mamba_scan(float* __restrict__ st,
                           const float* __restrict__ acs)
{
    long idx = (long)blockIdx.x * blockDim.x + threadIdx.x;
    if (idx >= (long)BATCH*NH*DH*DSTATE) return;
    int n = (int)(idx % DSTATE);
    int p = (int)((idx / DSTATE) % DH);
    int h = (int)((idx / ((long)DSTATE*DH)) % NH);
    int b = (int)( idx / ((long)DSTATE*DH*NH));

    float carry = 0.f;
    for (int c = 0; c < NC; ++c) {
        int bc = b*NC + c;
        long o = ((long)(bc*NH + h)*DH + p)*DSTATE + n;
        float s = st[o];
        st[o] = carry;
        float dchunk = expf(acs[((long)bc*CHK + CHK-1)*NH + h]);
        carry = carry*dchunk + s;
    }
}

// ======================================================================
// MFMA SSD y kernel (unchanged from passing round-7 version)
// ======================================================================
__launch_bounds__(256, 2)
__global__ void mamba_ssd_y(const float* __restrict__ xBC,
                            const float* __restrict__ CB,
                            const float* __restrict__ dt,
                            const float* __restrict__ acs,
                            const float* __restrict__ prevs,
                            const float* __restrict__ Dp,
                            float* __restrict__ y)
{
    constexpr int LK = 40;   // 32 + 8 pad shorts; rows 80B (16B-aligned)
    __shared__ unsigned short sPhi[256 * LK];
    __shared__ unsigned short sPlo[256 * LK];
    __shared__ unsigned short sXh[64 * LK];
    __shared__ unsigned short sXl[64 * LK];
    __shared__ float sAi[CHK];
    __shared__ float sDt[CHK];

    const int blk = blockIdx.x;       // bc*NH + h
    const int h  = blk % NH;
    const int bc = blk / NH;
    const int tid  = threadIdx.x;
    const int lane = tid & 63;
    const int w    = tid >> 6;
    const int fr   = lane & 15;
    const int fkb  = (lane >> 4) * 8;

    {
        long bl = (long)bc * CHK + tid;
        sAi[tid] = acs[bl * NH + h];
        sDt[tid] = dt [bl * NH + h];
    }
    __syncthreads();

    const float ai_r = sAi[tid];
    const float ei_r = expf(ai_r);

    f32x4 acc[4][4];
#pragma unroll
    for (int i = 0; i < 4; ++i)
#pragma unroll
        for (int j = 0; j < 4; ++j) acc[i][j] = (f32x4){0.f, 0.f, 0.f, 0.f};

    const float* CBrow = CB + (long)bc * CHK * CHK + (long)tid * CHK;

    // ---------------- part 1: intra-chunk, K = j (256) ----------------
    for (int j0 = 0; j0 < CHK; j0 += 32) {
        {
            const int i = tid;
#pragma unroll
            for (int q = 0; q < 8; ++q) {
                const int jb = j0 + q * 4;
                float4 cb = *reinterpret_cast<const float4*>(&CBrow[jb]);
                float vals[4] = {cb.x, cb.y, cb.z, cb.w};
                unsigned short hh[4], ll[4];
#pragma unroll
                for (int e = 0; e < 4; ++e) {
                    int j = jb + e;
                    float v = (j <= i) ? vals[e] * expf(ai_r - sAi[j]) * sDt[j] : 0.f;
                    hh[e] = f2bf(v);
                    ll[e] = f2bf(v - bf2f(hh[e]));
                }
                *reinterpret_cast<ushort4*>(&sPhi[i * LK + q * 4]) = make_ushort4(hh[0], hh[1], hh[2], hh[3]);
                *reinterpret_cast<ushort4*>(&sPlo[i * LK + q * 4]) = make_ushort4(ll[0], ll[1], ll[2], ll[3]);
            }
        }
        {
            const int j  = tid >> 3;
            const int p8 = (tid & 7) * 8;
            const float* xr = &xBC[((long)bc * CHK + j0 + j) * CONVD + h * DH + p8];
            float4 a = *reinterpret_cast<const float4*>(xr);
            float4 b = *reinterpret_cast<const float4*>(xr + 4);
            float vv[8] = {a.x, a.y, a.z, a.w, b.x, b.y, b.z, b.w};
#pragma unroll
            for (int e = 0; e < 8; ++e) {
                const int p  = p8 + e;
                const int js = j ^ ((((p >> 3) & 3)) << 3);
                unsigned short hh = f2bf(vv[e]);
                sXh[p * LK + js] = hh;
                sXl[p * LK + js] = f2bf(vv[e] - bf2f(hh));
            }
        }
        __syncthreads();
        {
            bf16x8 xh[4], xl[4];
#pragma unroll
            for (int ni = 0; ni < 4; ++ni) {
                const int xr_ = ni * 16 + fr;
                const int ks  = fkb ^ ((((xr_ >> 3) & 3)) << 3);
                xh[ni] = *reinterpret_cast<const bf16x8*>(&sXh[xr_ * LK + ks]);
                xl[ni] = *reinterpret_cast<const bf16x8*>(&sXl[xr_ * LK + ks]);
            }
#pragma unroll
            for (int mi = 0; mi < 4; ++mi) {
                const int rbase = mi * 64 + w * 16;
                if (j0 <= rbase + 15) {
                    const int r = rbase + fr;
                    bf16x8 ph = *reinterpret_cast<const bf16x8*>(&sPhi[r * LK + fkb]);
                    bf16x8 pl = *reinterpret_cast<const bf16x8*>(&sPlo[r * LK + fkb]);
#pragma unroll
                    for (int ni = 0; ni < 4; ++ni) {
                        acc[mi][ni] = __builtin_amdgcn_mfma_f32_16x16x32_bf16(ph, xh[ni], acc[mi][ni], 0, 0, 0);
                        acc[mi][ni] = __builtin_amdgcn_mfma_f32_16x16x32_bf16(pl, xh[ni], acc[mi][ni], 0, 0, 0);
                        acc[mi][ni] = __builtin_amdgcn_mfma_f32_16x16x32_bf16(ph, xl[ni], acc[mi][ni], 0, 0, 0);
                    }
                }
            }
        }
        __syncthreads();
    }

    // ---------------- part 2: inter-chunk, K = n (128) ----------------
    for (int n0 = 0; n0 < DSTATE; n0 += 32) {
        {
            const float* Crow = &xBC[((long)bc * CHK + tid) * CONVD + DI + DSTATE + n0];
#pragma unroll
            for (int q = 0; q < 8; ++q) {
                float4 c = *reinterpret_cast<const float4*>(&Crow[q * 4]);
                float vals[4] = {c.x * ei_r, c.y * ei_r, c.z * ei_r, c.w * ei_r};
                unsigned short hh[4], ll[4];
#pragma unroll
                for (int e = 0; e < 4; ++e) {
                    hh[e] = f2bf(vals[e]);
                    ll[e] = f2bf(vals[e] - bf2f(hh[e]));
                }
                *reinterpret_cast<ushort4*>(&sPhi[tid * LK + q * 4]) = make_ushort4(hh[0], hh[1], hh[2], hh[3]);
                *reinterpret_cast<ushort4*>(&sPlo[tid * LK + q * 4]) = make_ushort4(ll[0], ll[1], ll[2], ll[3]);
            }
        }
        {
            const int p  = tid >> 2;
            const int n8 = (tid & 3) * 8;
            const float* pr = &prevs[((long)blk * DH + p) * DSTATE + n0 + n8];
            float4 a = *reinterpret_cast<const float4*>(pr);
            float4 b = *reinterpret_cast<const float4*>(pr + 4);
            us8 hh, ll;
            cvt8(a, b, hh, ll);
            const int ns = n8 ^ ((((p >> 3) & 3)) << 3);
            *reinterpret_cast<us8*>(&sXh[p * LK + ns]) = hh;
            *reinterpret_cast<us8*>(&sXl[p * LK + ns]) = ll;
        }
        __syncthreads();
        {
            bf16x8 vh[4], vl[4];
#pragma unroll
            for (int ni = 0; ni < 4; ++ni) {
                const int xr_ = ni * 16 + fr;
                const int ks  = fkb ^ ((((xr_ >> 3) & 3)) << 3);
                vh[ni] = *reinterpret_cast<const bf16x8*>(&sXh[xr_ * LK + ks]);
                vl[ni] = *reinterpret_cast<const bf16x8*>(&sXl[xr_ * LK + ks]);
            }
#pragma unroll
            for (int mi = 0; mi < 4; ++mi) {
                const int r = mi * 64 + w * 16 + fr;
                bf16x8 ch = *reinterpret_cast<const bf16x8*>(&sPhi[r * LK + fkb]);
                bf16x8 cl = *reinterpret_cast<const bf16x8*>(&sPlo[r * LK + fkb]);
#pragma unroll
                for (int ni = 0; ni < 4; ++ni) {
                    acc[mi][ni] = __builtin_amdgcn_mfma_f32_16x16x32_bf16(ch, vh[ni], acc[mi][ni], 0, 0, 0);
                    acc[mi][ni] = __builtin_amdgcn_mfma_f32_16x16x32_bf16(cl, vh[ni], acc[mi][ni], 0, 0, 0);
                    acc[mi][ni] = __builtin_amdgcn_mfma_f32_16x16x32_bf16(ch, vl[ni], acc[mi][ni], 0, 0, 0);
                }
            }
        }
        __syncthreads();
    }

    // ---------------- epilogue: + D*x, store ----------------
    const float Dh = Dp[h];
    const int crow = (lane >> 4) * 4;
#pragma unroll
    for (int mi = 0; mi < 4; ++mi) {
        const int ib = mi * 64 + w * 16 + crow;
#pragma unroll
        for (int e = 0; e < 4; ++e) {
            const long bl = (long)bc * CHK + ib + e;
#pragma unroll
            for (int ni = 0; ni < 4; ++ni) {
                const int p = ni * 16 + fr;
                float xv = xBC[bl * CONVD + h * DH + p];
                y[bl * DI + h * DH + p] = acc[mi][ni][e] + Dh * xv;
            }
        }
    }
}

// ======================================================================
// gate + RMSNorm, IN-PLACE converting the fp32 y row into split2 bf16
// [hi(DI)|lo(DI)] (same 8KB footprint). out_proj reads it as As directly.
// ======================================================================
__launch_bounds__(256)
__global__ void mamba_gate_norm(const float* __restrict__ zbuf,
                                const float* __restrict__ norm_w,
                                float* __restrict__ y)
{
    long bl = blockIdx.x;
    const float* zrow = zbuf + bl*DI;
    float* yrow = y + bl*DI;
    const int base = threadIdx.x * 8;

    float vals[8];
    float ss = 0.f;
#pragma unroll
    for (int half = 0; half < 2; ++half) {
        float4 zv = *reinterpret_cast<const float4*>(&zrow[base + half*4]);
        float4 yv = *reinterpret_cast<const float4*>(&yrow[base + half*4]);
        float zz[4] = {zv.x, zv.y, zv.z, zv.w};
        float yy[4] = {yv.x, yv.y, yv.z, yv.w};
#pragma unroll
        for (int t = 0; t < 4; ++t) {
            float v = yy[t] * (zz[t] / (1.f + expf(-zz[t])));
            vals[half*4+t] = v;
            ss += v*v;
        }
    }
#pragma unroll
    for (int o = 1; o < 64; o <<= 1) ss += __shfl_xor(ss, o, 64);

    __shared__ float red[4];
    int wid = threadIdx.x >> 6;
    if ((threadIdx.x & 63) == 0) red[wid] = ss;
    __syncthreads();   // also guarantees all yrow reads complete before writes
    ss = red[0] + red[1] + red[2] + red[3];
    float scale = rsqrtf(ss / DI + 1e-5f);

    unsigned short hi[8], lo[8];
#pragma unroll
    for (int t = 0; t < 8; ++t) {
        float v = vals[t] * scale * norm_w[base + t];
        hi[t] = f2bf(v);
        lo[t] = f2bf(v - bf2f(hi[t]));
    }
    unsigned short* d = reinterpret_cast<unsigned short*>(yrow);
#pragma unroll
    for (int half = 0; half < 2; ++half) {
        int k = base + half*4;
        *reinterpret_cast<ushort4*>(&d[k])      = make_ushort4(hi[half*4+0], hi[half*4+1], hi[half*4+2], hi[half*4+3]);
        *reinterpret_cast<ushort4*>(&d[DI + k]) = make_ushort4(lo[half*4+0], lo[half*4+1], lo[half*4+2], lo[half*4+3]);
    }
}

// ======================================================================
extern "C" void kernel_launch(void* const* d_in, const int* in_sizes, int n_in,
                              void* d_out, int out_size, void* d_ws, size_t ws_size,
                              hipStream_t stream)
{
    const float* u         = (const float*)d_in[0];
    const float* in_proj_w = (const float*)d_in[1];
    const float* conv_w    = (const float*)d_in[2];
    const float* conv_b    = (const float*)d_in[3];
    const float* dt_bias   = (const float*)d_in[4];
    const float* A_log     = (const float*)d_in[5];
    const float* Dp        = (const float*)d_in[6];
    const float* norm_w    = (const float*)d_in[7];
    const float* out_proj_w= (const float*)d_in[8];
    float* out = (float*)d_out;

    char* ws = (char*)d_ws;
    float* zbuf  = (float*)(ws + OFF_Z);
    float* xpre  = (float*)(ws + OFF_XPRE);
    float* yb    = xpre;                       // alias: xpre dead after conv
    float* dtraw = (float*)(ws + OFF_DTRW);
    float* xBC   = (float*)(ws + OFF_XBC);
    float* dtb   = (float*)(ws + OFF_DT);
    float* acs   = (float*)(ws + OFF_ACS);
    float* CBb   = (float*)(ws + OFF_CB);
    unsigned short* wInS  = (unsigned short*)(ws + OFF_WIS);
    unsigned short* wOutS = (unsigned short*)(ws + OFF_WOS);
    unsigned short* uS    = (unsigned short*)d_out;  // u split2 in d_out (dead by states)
    float* stb = out;                          // states/prevs live in d_out later

    // 0) split2 weights + u
    {
        long total = (long)DPROJ * (DM/4);
        mamba_split2<<<(unsigned)((total+255)/256), 256, 0, stream>>>(in_proj_w, wInS, DPROJ, DM);
        total = (long)DM * (DI/4);
        mamba_split2<<<(unsigned)((total+255)/256), 256, 0, stream>>>(out_proj_w, wOutS, DM, DI);
        total = (long)BL * (DM/4);
        mamba_split2<<<(unsigned)((total+255)/256), 256, 0, stream>>>(u, uS, BL, DM);
    }
    // 1) in_proj as 3 column-range GEMMs (both operands pre-split bf16)
    {
        dim3 gz(DI/128, BL/128);      // z: rows [0, 2048)
        gemm_ssplit<<<gz, 256, 0, stream>>>(uS, wInS, DI, zbuf, DI, DM);
        dim3 gx(CONVD/128, BL/128);   // xBC: rows [2048, 4352)
        gemm_ssplit<<<gx, 256, 0, stream>>>(uS, wInS + (long)DI*2*DM, CONVD, xpre, CONVD, DM);
        dim3 gd(1, BL/128);           // dt: rows [4352, 4384), N-guarded
        gemm_ssplit<<<gd, 256, 0, stream>>>(uS, wInS + (long)(DI+CONVD)*2*DM, NH, dtraw, NH, DM);
    }
    // 2) conv + silu
    {
        long total = (long)BL*(CONVD/4);
        mamba_conv_silu<<<(unsigned)((total+255)/256), 256, 0, stream>>>(xpre, conv_w, conv_b, xBC);
    }
    // 3) dt softplus + cumsum
    mamba_dt_cumsum<<<BATCH*NC*NH, CHK, 0, stream>>>(dtraw, dt_bias, A_log, dtb, acs);
    // 4) CB batched GEMM (fp32, small)
    {
        dim3 grid(CHK/64, CHK/64, BATCH*NC);
        mamba_gemm_nt<64,64,16,4,4><<<grid, 256, 0, stream>>>(
            xBC + DI + DSTATE, xBC + DI, CBb,
            CHK, CHK, DSTATE, CONVD, CONVD, CHK,
            (long)CHK*CONVD, (long)CHK*CONVD, (long)CHK*CHK);
    }
    // 5) per-chunk states (into d_out, overwrites dead uS)
    mamba_states<<<BATCH*NC*NH, 256, 0, stream>>>(xBC, dtb, acs, stb);
    // 6) inter-chunk scan, in-place
    {
        long total = (long)BATCH*NH*DH*DSTATE;
        mamba_scan<<<(unsigned)((total+255)/256), 256, 0, stream>>>(stb, acs);
    }
    // 7) y via MFMA (intra + inter + D skip)
    mamba_ssd_y<<<BATCH*NC*NH, 256, 0, stream>>>(xBC, CBb, dtb, acs, stb, Dp, yb);
    // 8) gate + RMSNorm, in-place convert to split2 bf16
    mamba_gate_norm<<<BL, 256, 0, stream>>>(zbuf, norm_w, yb);
    // 9) out_proj (both operands pre-split bf16, overwrites d_out)
    {
        dim3 grid(DM/128, BL/128);
        gemm_ssplit<<<grid, 256, 0, stream>>>((unsigned short*)yb, wOutS, DM, out, DM, DI);
    }
}